// Round 10
// baseline (1253.001 us; speedup 1.0000x reference)
//
#include <hip/hip_runtime.h>
#include <cstdint>

#define NN 100000
#define NE 250000
#define MP 100096   // 391 * 256
#define MSTRIP 391
#define SCAN_B 256
#define NBLK ((NN + SCAN_B - 1) / SCAN_B)   // 391
#define NSLOT 32

using bf16x8 = __attribute__((ext_vector_type(8))) __bf16;
using f32x4v = __attribute__((ext_vector_type(4))) float;

__device__ __forceinline__ unsigned short f2bf(float f) {
  union { float f; uint32_t u; } v; v.f = f;
  uint32_t r = v.u + 0x7FFFu + ((v.u >> 16) & 1u);
  return (unsigned short)(r >> 16);
}
__device__ __forceinline__ float bf2f(unsigned short u) {
  union { uint32_t u; float f; } v; v.u = ((uint32_t)u) << 16;
  return v.f;
}

__device__ __forceinline__ void ld_lds16(const void* g, void* l) {
  __builtin_amdgcn_global_load_lds(
      (const __attribute__((address_space(1))) void*)g,
      (__attribute__((address_space(3))) void*)l, 16, 0, 0);
}

// ---------------- prep (ALL 5 layers, one dispatch): weights->bf16 transposed,
// combos, biases, and zero all BN accumulators.
#define PER_L (640*320 + 384*640 + 3600 + 300 + 640 + 384)   // 455484
#define ZERO_N (5 * 2 * NSLOT * 384)                          // 491520
#define PREP_TOT (5 * PER_L + ZERO_N)
__global__ void prep_kernel(const float* __restrict__ W1, const float* __restrict__ W2,
                            const float* __restrict__ ee1, const float* __restrict__ ee2,
                            const float* __restrict__ b1, const float* __restrict__ b2,
                            unsigned short* __restrict__ wt1, unsigned short* __restrict__ wt2,
                            float* __restrict__ combo, float* __restrict__ selfv,
                            float* __restrict__ b1p, float* __restrict__ b2p,
                            float* __restrict__ bnzero) {
  int i = blockIdx.x * 256 + threadIdx.x;
  if (i < 5 * PER_L) {
    int l = i / PER_L, j = i - l * PER_L;
    if (j < 640 * 320) {                     // wt1[l][n][k] = W1[l][k][n], pad 640x320
      int n = j / 320, k = j % 320;
      float v = (n < 600 && k < 300) ? W1[(size_t)l * 180000 + k * 600 + n] : 0.f;
      wt1[l * 204800 + j] = f2bf(v); return;
    }
    j -= 640 * 320;
    if (j < 384 * 640) {                     // wt2[l][n][k] = W2[l][k][n], pad 384x640
      int n = j / 640, k = j % 640;
      float v = (n < 300 && k < 600) ? W2[(size_t)l * 180000 + k * 300 + n] : 0.f;
      wt2[l * 245760 + j] = f2bf(v); return;
    }
    j -= 384 * 640;
    if (j < 3600) {                          // 12 edge-embedding combos [12][300]
      int idx = j / 300, d = j % 300;
      int a = idx / 3, b = idx % 3;
      combo[l * 3600 + j] = ee1[l * 1800 + a * 300 + d] + ee2[l * 900 + b * 300 + d]; return;
    }
    j -= 3600;
    if (j < 300) { selfv[l * 300 + j] = ee1[l * 1800 + 4 * 300 + j] + ee2[l * 900 + j]; return; }
    j -= 300;
    if (j < 640) { b1p[l * 640 + j] = (j < 600) ? b1[l * 600 + j] : 0.f; return; }
    j -= 640;
    b2p[l * 384 + j] = (j < 300) ? b2[l * 300 + j] : 0.f; return;
  }
  i -= 5 * PER_L;
  if (i < ZERO_N) bnzero[i] = 0.f;
}

// ---------------- CSR build: degree histogram
__global__ void deg_kernel(const int* __restrict__ ei, int* __restrict__ deg) {
  int e = blockIdx.x * 256 + threadIdx.x;
  if (e >= NE) return;
  atomicAdd(&deg[ei[NE + e]], 1);
}

// ---------------- exclusive scan (3 kernels)
__global__ void scan1_kernel(const int* __restrict__ deg, int* __restrict__ off,
                             int* __restrict__ bsum) {
  __shared__ int tmp[SCAN_B];
  int b = blockIdx.x, t = threadIdx.x;
  int i = b * SCAN_B + t;
  int v = (i < NN) ? deg[i] : 0;
  tmp[t] = v;
  __syncthreads();
  for (int s = 1; s < SCAN_B; s <<= 1) {
    int a = (t >= s) ? tmp[t - s] : 0;
    __syncthreads();
    tmp[t] += a;
    __syncthreads();
  }
  if (i < NN) off[i] = tmp[t] - v;           // exclusive
  if (t == SCAN_B - 1) bsum[b] = tmp[t];
}
__global__ void scan2_kernel(int* __restrict__ bsum) {
  if (threadIdx.x == 0) {
    int acc = 0;
    for (int b = 0; b < NBLK; ++b) { int v = bsum[b]; bsum[b] = acc; acc += v; }
  }
}
__global__ void scan3_kernel(const int* __restrict__ bsum, int* __restrict__ off,
                             int* __restrict__ cursor) {
  int i = blockIdx.x * SCAN_B + threadIdx.x;
  if (i >= NN) return;
  int o = off[i] + bsum[blockIdx.x];
  off[i] = o;
  cursor[i] = o;
}

// ---------------- CSR fill: list[p] = src*16 + combo_idx
__global__ void fill_kernel(const int* __restrict__ ei, const int* __restrict__ ea,
                            int* __restrict__ cursor, int* __restrict__ list) {
  int e = blockIdx.x * 256 + threadIdx.x;
  if (e >= NE) return;
  int s = ei[e], d = ei[NE + e];
  int c = ea[2 * e] * 3 + ea[2 * e + 1];
  int p = atomicAdd(&cursor[d], 1);
  list[p] = s * 16 + c;
}

// ---------------- gather (fused BN-apply + ReLU + aggregate + (1+eps)* + bf16 cast)
// MODE 0: source row = x_emb1[x0[s]] + x_emb2[x1[s]]          (layer 0, no BN)
// MODE 1: source row = relu(bf16z[s]*bnA + bnB)               (layers 1..4)
template <int MODE>
__global__ void gather_kernel(const unsigned short* __restrict__ zsrc,
                              const int* __restrict__ x, const float* __restrict__ e1,
                              const float* __restrict__ e2,
                              const float* __restrict__ bnA, const float* __restrict__ bnB,
                              const int* __restrict__ off, const int* __restrict__ deg,
                              const int* __restrict__ list,
                              const float* __restrict__ combo, const float* __restrict__ selfv,
                              const float* __restrict__ eps, int l,
                              unsigned short* __restrict__ abf) {
  int i = blockIdx.x * 256 + threadIdx.x;
  if (i >= NN * 75) return;
  int r = i / 75, q = i % 75;
  float4 a4, b4;
  if (MODE == 1) { a4 = ((const float4*)bnA)[q]; b4 = ((const float4*)bnB)[q]; }

  const ushort4* z4 = (const ushort4*)zsrc;
  const float4* c4 = (const float4*)combo;

  auto loadrow = [&](int s) -> float4 {
    float4 hv;
    if (MODE == 0) {
      float4 u = ((const float4*)(e1 + (size_t)x[2 * s] * 300))[q];
      float4 v = ((const float4*)(e2 + (size_t)x[2 * s + 1] * 300))[q];
      hv.x = u.x + v.x; hv.y = u.y + v.y; hv.z = u.z + v.z; hv.w = u.w + v.w;
    } else {
      ushort4 zv = z4[(size_t)s * 96 + q];
      hv.x = fmaxf(bf2f(zv.x) * a4.x + b4.x, 0.f);
      hv.y = fmaxf(bf2f(zv.y) * a4.y + b4.y, 0.f);
      hv.z = fmaxf(bf2f(zv.z) * a4.z + b4.z, 0.f);
      hv.w = fmaxf(bf2f(zv.w) * a4.w + b4.w, 0.f);
    }
    return hv;
  };

  float4 acc = loadrow(r);
  float4 sv = ((const float4*)selfv)[q];
  acc.x += sv.x; acc.y += sv.y; acc.z += sv.z; acc.w += sv.w;

  int p0 = off[r], dn = deg[r];
  for (int p = 0; p < dn; ++p) {
    int pk = list[p0 + p];
    int s = pk >> 4, c = pk & 15;
    float4 hv = loadrow(s);
    float4 cv = c4[c * 75 + q];
    acc.x += hv.x + cv.x; acc.y += hv.y + cv.y;
    acc.z += hv.z + cv.z; acc.w += hv.w + cv.w;
  }
  float sc = 1.f + eps[l];
  ushort4 o;
  o.x = f2bf(acc.x * sc); o.y = f2bf(acc.y * sc);
  o.z = f2bf(acc.z * sc); o.w = f2bf(acc.w * sc);
  *(ushort4*)(abf + (size_t)r * 320 + q * 4) = o;
}

// ---------------- bf16 MFMA GEMM (r8 structure): 8 waves, BM=256 x BN=128.
// Double-buffered LDS, counted-vmcnt prefetch, XCD remap (wid%8 = strip group).
// STATS: per-column sum/sumsq of output (rows < NN), slot-split 32x.
template <int LDA, int LDB, int NS, int NT, bool RELU, bool OBF16, bool STATS>
__global__ __launch_bounds__(512, 4) void gemm_kernel(
    const unsigned short* __restrict__ A, const unsigned short* __restrict__ B,
    const float* __restrict__ bias, void* __restrict__ C, int K,
    float* __restrict__ bnsum, float* __restrict__ bnsum2) {
  __shared__ unsigned short As[2][256 * 32];   // 2 x 16 KB
  __shared__ unsigned short Bs[2][128 * 32];   // 2 x 8 KB
  const int tid = threadIdx.x;
  const int lane = tid & 63;
  const int w = tid >> 6;            // 8 waves: wr = w>>1 (M), wc = w&1 (N)
  const int wr = w >> 1, wc = w & 1;
  const int l15 = lane & 15, l4 = lane >> 4;

  const int wid = blockIdx.x + gridDim.x * blockIdx.y;
  const int bmi = (wid & 7) + 8 * (wid / (8 * NT));
  const int ny  = (wid >> 3) % NT;
  if (bmi >= MSTRIP) return;
  const int bm = bmi * 256;
  const int bn = ny * 128;

  auto stage = [&](int buf, int kk) {
#pragma unroll
    for (int it = 0; it < 2; ++it) {
      int s = it * 512 + tid;
      int row = s >> 2, kbl = s & 3;
      int kbg = kbl ^ ((row >> 1) & 3);        // pre-swizzled global source
      ld_lds16(A + (size_t)(bm + row) * LDA + kk + kbg * 8, &As[buf][s * 8]);
    }
    {
      int s = tid;
      int row = s >> 2, kbl = s & 3;
      int kbg = kbl ^ ((row >> 1) & 3);
      ld_lds16(B + (size_t)(bn + row) * LDB + kk + kbg * 8, &Bs[buf][s * 8]);
    }
  };

  f32x4v acc[4][4] = {};
  const int nt = K / 32;

  stage(0, 0);
  for (int t = 0; t < nt; ++t) {
    const int cur = t & 1;
    if (t + 1 < nt) {
      stage(cur ^ 1, (t + 1) * 32);                     // prefetch next tile (3 loads)
      asm volatile("s_waitcnt vmcnt(3)" ::: "memory");  // my stage(t) loads landed
    } else {
      asm volatile("s_waitcnt vmcnt(0)" ::: "memory");
    }
    __builtin_amdgcn_s_barrier();                       // raw: no vmcnt(0) drain
    asm volatile("" ::: "memory");

    bf16x8 af[4], bfr[4];
#pragma unroll
    for (int mi = 0; mi < 4; ++mi) {
      int r = wr * 64 + mi * 16 + l15;
      int kb = l4 ^ ((r >> 1) & 3);            // swizzled read
      af[mi] = *reinterpret_cast<const bf16x8*>(&As[cur][(r * 4 + kb) * 8]);
    }
#pragma unroll
    for (int ni = 0; ni < 4; ++ni) {
      int r = wc * 64 + ni * 16 + l15;
      int kb = l4 ^ ((r >> 1) & 3);
      bfr[ni] = *reinterpret_cast<const bf16x8*>(&Bs[cur][(r * 4 + kb) * 8]);
    }
#pragma unroll
    for (int mi = 0; mi < 4; ++mi)
#pragma unroll
      for (int ni = 0; ni < 4; ++ni)
        acc[mi][ni] = __builtin_amdgcn_mfma_f32_16x16x32_bf16(af[mi], bfr[ni], acc[mi][ni], 0, 0, 0);

    __builtin_amdgcn_s_barrier();                       // buf free for re-stage
    asm volatile("" ::: "memory");
  }

  const int slot = wid & (NSLOT - 1);
#pragma unroll
  for (int ni = 0; ni < 4; ++ni) {
    int col = bn + wc * 64 + ni * 16 + l15;
    float bv = bias[col];
    float s = 0.f, s2 = 0.f;
#pragma unroll
    for (int mi = 0; mi < 4; ++mi) {
      int row0 = bm + wr * 64 + mi * 16 + (l4 << 2);
#pragma unroll
      for (int r = 0; r < 4; ++r) {
        float v = acc[mi][ni][r] + bv;
        if (RELU) v = fmaxf(v, 0.f);
        if (OBF16) ((unsigned short*)C)[(size_t)(row0 + r) * NS + col] = f2bf(v);
        else       ((float*)C)[(size_t)(row0 + r) * NS + col] = v;
        if (STATS && (row0 + r) < NN) { s += v; s2 += v * v; }
      }
    }
    if (STATS) {
      s  += __shfl_xor(s, 16);  s  += __shfl_xor(s, 32);
      s2 += __shfl_xor(s2, 16); s2 += __shfl_xor(s2, 32);
      if (l4 == 0) {
        atomicAdd(&bnsum[slot * 384 + col], s);
        atomicAdd(&bnsum2[slot * 384 + col], s2);
      }
    }
  }
}

// ---------------- narrow GEMM2 tail: cols 256..319 (BN=64), 4 waves, BM=256.
// A = z1 [MP][640], B = wt2 rows 256..319. Same dbuf/counted-vmcnt structure.
__global__ __launch_bounds__(256, 2) void gemm2_narrow_kernel(
    const unsigned short* __restrict__ A, const unsigned short* __restrict__ B,
    const float* __restrict__ bias, unsigned short* __restrict__ C,
    float* __restrict__ bnsum, float* __restrict__ bnsum2) {
  __shared__ unsigned short As[2][256 * 32];   // 2 x 16 KB
  __shared__ unsigned short Bs[2][64 * 32];    // 2 x 4 KB
  const int tid = threadIdx.x;
  const int lane = tid & 63;
  const int w = tid >> 6;            // 4 waves, wave w owns rows [w*64, w*64+64)
  const int l15 = lane & 15, l4 = lane >> 4;
  const int bmi = blockIdx.x;
  if (bmi >= MSTRIP) return;
  const int bm = bmi * 256;
  const int bn = 256;

  auto stage = [&](int buf, int kk) {
#pragma unroll
    for (int it = 0; it < 4; ++it) {
      int s = it * 256 + tid;
      int row = s >> 2, kbl = s & 3;
      int kbg = kbl ^ ((row >> 1) & 3);
      ld_lds16(A + (size_t)(bm + row) * 640 + kk + kbg * 8, &As[buf][s * 8]);
    }
    {
      int s = tid;
      int row = s >> 2, kbl = s & 3;   // row in [0,64)
      int kbg = kbl ^ ((row >> 1) & 3);
      ld_lds16(B + (size_t)(bn + row) * 640 + kk + kbg * 8, &Bs[buf][s * 8]);
    }
  };

  f32x4v acc[4][4] = {};
  stage(0, 0);
  for (int t = 0; t < 20; ++t) {
    const int cur = t & 1;
    if (t + 1 < 20) {
      stage(cur ^ 1, (t + 1) * 32);
      asm volatile("s_waitcnt vmcnt(5)" ::: "memory");
    } else {
      asm volatile("s_waitcnt vmcnt(0)" ::: "memory");
    }
    __builtin_amdgcn_s_barrier();
    asm volatile("" ::: "memory");

    bf16x8 af[4], bfr[4];
#pragma unroll
    for (int mi = 0; mi < 4; ++mi) {
      int r = w * 64 + mi * 16 + l15;
      int kb = l4 ^ ((r >> 1) & 3);
      af[mi] = *reinterpret_cast<const bf16x8*>(&As[cur][(r * 4 + kb) * 8]);
    }
#pragma unroll
    for (int ni = 0; ni < 4; ++ni) {
      int r = ni * 16 + l15;
      int kb = l4 ^ ((r >> 1) & 3);
      bfr[ni] = *reinterpret_cast<const bf16x8*>(&Bs[cur][(r * 4 + kb) * 8]);
    }
#pragma unroll
    for (int mi = 0; mi < 4; ++mi)
#pragma unroll
      for (int ni = 0; ni < 4; ++ni)
        acc[mi][ni] = __builtin_amdgcn_mfma_f32_16x16x32_bf16(af[mi], bfr[ni], acc[mi][ni], 0, 0, 0);

    __builtin_amdgcn_s_barrier();
    asm volatile("" ::: "memory");
  }

  const int slot = bmi & (NSLOT - 1);
#pragma unroll
  for (int ni = 0; ni < 4; ++ni) {
    int col = bn + ni * 16 + l15;
    float bv = bias[col];
    float s = 0.f, s2 = 0.f;
#pragma unroll
    for (int mi = 0; mi < 4; ++mi) {
      int row0 = bm + w * 64 + mi * 16 + (l4 << 2);
#pragma unroll
      for (int r = 0; r < 4; ++r) {
        float v = acc[mi][ni][r] + bv;
        C[(size_t)(row0 + r) * 384 + col] = f2bf(v);
        if ((row0 + r) < NN) { s += v; s2 += v * v; }
      }
    }
    s  += __shfl_xor(s, 16);  s  += __shfl_xor(s, 32);
    s2 += __shfl_xor(s2, 16); s2 += __shfl_xor(s2, 32);
    if (l4 == 0) {
      atomicAdd(&bnsum[slot * 384 + col], s);
      atomicAdd(&bnsum2[slot * 384 + col], s2);
    }
  }
}

__global__ void bnfinal_kernel(const float* __restrict__ bnsum, const float* __restrict__ bnsum2,
                               const float* __restrict__ gamma, const float* __restrict__ beta,
                               int l, float* __restrict__ Aout, float* __restrict__ Bout) {
  int c = threadIdx.x;
  if (c >= 300) return;
  float s = 0.f, s2 = 0.f;
  for (int k = 0; k < NSLOT; ++k) { s += bnsum[k * 384 + c]; s2 += bnsum2[k * 384 + c]; }
  float mean = s * (1.f / NN);
  float var = s2 * (1.f / NN) - mean * mean;
  var = fmaxf(var, 0.f);
  float inv = rsqrtf(var + 1e-5f);
  float a = gamma[l * 300 + c] * inv;
  Aout[c] = a;
  Bout[c] = beta[l * 300 + c] - mean * a;
}

// ---------------- final BN apply (layer 4, no ReLU): d_out[N][300] = bf2f(z)*A + B
__global__ void bnapply_kernel(const unsigned short* __restrict__ z, const float* __restrict__ Ain,
                               const float* __restrict__ Bin, float* __restrict__ out) {
  int i = blockIdx.x * 256 + threadIdx.x;
  if (i >= NN * 75) return;
  int r = i / 75, q = i % 75;
  ushort4 zv = ((const ushort4*)z)[(size_t)r * 96 + q];
  float4 a = ((const float4*)Ain)[q];
  float4 b = ((const float4*)Bin)[q];
  float4 o;
  o.x = bf2f(zv.x) * a.x + b.x; o.y = bf2f(zv.y) * a.y + b.y;
  o.z = bf2f(zv.z) * a.z + b.z; o.w = bf2f(zv.w) * a.w + b.w;
  ((float4*)out)[i] = o;
}

// ---------------- workspace layout (bytes, all 256-aligned)
constexpr size_t OFF_Z    = 0;                               // z bf16 [MP][384]
constexpr size_t OFF_AB   = OFF_Z  + (size_t)MP * 384 * 2;   // abf16 [MP][320]
constexpr size_t OFF_Z1   = OFF_AB + (size_t)MP * 320 * 2;   // z1 bf16 [MP][640]
constexpr size_t OFF_WT1  = OFF_Z1 + (size_t)MP * 640 * 2;   // wt1 bf16 [5][640*320]
constexpr size_t OFF_WT2  = OFF_WT1 + (size_t)5 * 204800 * 2;// wt2 bf16 [5][384*640]
constexpr size_t OFF_CMB  = OFF_WT2 + (size_t)5 * 245760 * 2;// combo f32 [5][3600]
constexpr size_t OFF_SLF  = OFF_CMB + 5 * 3600 * 4;          // selfv f32 [5][300]
constexpr size_t OFF_B1   = OFF_SLF + 5 * 300 * 4 + 144;     // b1p f32 [5][640] (aligned)
constexpr size_t OFF_B2   = OFF_B1 + 5 * 640 * 4;            // b2p f32 [5][384]
constexpr size_t OFF_S1   = OFF_B2 + 5 * 384 * 4;            // bnsum  f32 [5][32][384]
constexpr size_t OFF_S2   = OFF_S1 + (size_t)5 * NSLOT * 384 * 4;  // bnsum2 (contiguous!)
constexpr size_t OFF_BA   = OFF_S2 + (size_t)5 * NSLOT * 384 * 4;
constexpr size_t OFF_BB   = OFF_BA + 1536;
constexpr size_t OFF_DEG  = OFF_BB + 1536;              // int[NN]
constexpr size_t OFF_OFFS = OFF_DEG + 400384;           // int[NN]
constexpr size_t OFF_CUR  = OFF_OFFS + 400384;          // int[NN]
constexpr size_t OFF_BS   = OFF_CUR + 400384;           // int[NBLK]
constexpr size_t OFF_LIST = OFF_BS + 2048;              // int[NE]

extern "C" void kernel_launch(void* const* d_in, const int* in_sizes, int n_in,
                              void* d_out, int out_size, void* d_ws, size_t ws_size,
                              hipStream_t stream) {
  const int*   x     = (const int*)d_in[0];
  const int*   ei    = (const int*)d_in[1];
  const int*   ea    = (const int*)d_in[2];
  const float* xe1   = (const float*)d_in[3];
  const float* xe2   = (const float*)d_in[4];
  const float* ee1   = (const float*)d_in[5];
  const float* ee2   = (const float*)d_in[6];
  const float* W1    = (const float*)d_in[7];
  const float* b1    = (const float*)d_in[8];
  const float* W2    = (const float*)d_in[9];
  const float* b2    = (const float*)d_in[10];
  const float* eps   = (const float*)d_in[11];
  const float* gamma = (const float*)d_in[12];
  const float* beta  = (const float*)d_in[13];

  char* ws = (char*)d_ws;
  unsigned short* zf    = (unsigned short*)(ws + OFF_Z);
  unsigned short* abf   = (unsigned short*)(ws + OFF_AB);
  unsigned short* z1    = (unsigned short*)(ws + OFF_Z1);
  unsigned short* wt1   = (unsigned short*)(ws + OFF_WT1);
  unsigned short* wt2   = (unsigned short*)(ws + OFF_WT2);
  float*          combo = (float*)(ws + OFF_CMB);
  float*          selfv = (float*)(ws + OFF_SLF);
  float*          b1p   = (float*)(ws + OFF_B1);
  float*          b2p   = (float*)(ws + OFF_B2);
  float*          bns   = (float*)(ws + OFF_S1);
  float*          bns2  = (float*)(ws + OFF_S2);
  float*          bnA   = (float*)(ws + OFF_BA);
  float*          bnB   = (float*)(ws + OFF_BB);
  int*            deg   = (int*)(ws + OFF_DEG);
  int*            offs  = (int*)(ws + OFF_OFFS);
  int*            cur   = (int*)(ws + OFF_CUR);
  int*            bsum  = (int*)(ws + OFF_BS);
  int*            list  = (int*)(ws + OFF_LIST);

  const int g_ew   = (NN * 75 + 255) / 256;
  const int g_e    = (NE + 255) / 256;
  const int g_prep = (PREP_TOT + 255) / 256;
  const int GX     = 392;   // 49 groups of 8 row-strips (1 idle strip: 391)

  // one-time per launch: zero abf (pad rows/cols stay 0 across layers), deg
  hipMemsetAsync(abf, 0, (size_t)MP * 320 * 2, stream);
  hipMemsetAsync(deg, 0, NN * 4, stream);

  // all-layer prep (weights, combos, biases, BN accumulator zeroing)
  prep_kernel<<<g_prep, 256, 0, stream>>>(W1, W2, ee1, ee2, b1, b2,
                                          wt1, wt2, combo, selfv, b1p, b2p, bns);

  // CSR build (graph static across layers)
  deg_kernel<<<g_e, 256, 0, stream>>>(ei, deg);
  scan1_kernel<<<NBLK, SCAN_B, 0, stream>>>(deg, offs, bsum);
  scan2_kernel<<<1, 64, 0, stream>>>(bsum);
  scan3_kernel<<<NBLK, SCAN_B, 0, stream>>>(bsum, offs, cur);
  fill_kernel<<<g_e, 256, 0, stream>>>(ei, ea, cur, list);

  for (int l = 0; l < 5; ++l) {
    float* bns_l  = bns  + (size_t)l * NSLOT * 384;
    float* bns2_l = bns2 + (size_t)l * NSLOT * 384;
    if (l == 0)
      gather_kernel<0><<<g_ew, 256, 0, stream>>>(zf, x, xe1, xe2, bnA, bnB,
                                                 offs, deg, list, combo + l * 3600,
                                                 selfv + l * 300, eps, l, abf);
    else
      gather_kernel<1><<<g_ew, 256, 0, stream>>>(zf, x, xe1, xe2, bnA, bnB,
                                                 offs, deg, list, combo + l * 3600,
                                                 selfv + l * 300, eps, l, abf);
    gemm_kernel<320, 320, 640, 5, true, true, false><<<dim3(GX, 5), 512, 0, stream>>>(
        abf, wt1 + (size_t)l * 204800, b1p + l * 640, (void*)z1, 320, bns_l, bns2_l);
    gemm_kernel<640, 640, 384, 2, false, true, true><<<dim3(GX, 2), 512, 0, stream>>>(
        z1, wt2 + (size_t)l * 245760, b2p + l * 384, (void*)zf, 640, bns_l, bns2_l);
    gemm2_narrow_kernel<<<GX, 256, 0, stream>>>(
        z1, wt2 + (size_t)l * 245760, b2p + l * 384, zf, bns_l, bns2_l);
    bnfinal_kernel<<<1, 384, 0, stream>>>(bns_l, bns2_l, gamma, beta, l, bnA, bnB);
  }
  bnapply_kernel<<<g_ew, 256, 0, stream>>>(zf, bnA, bnB, (float*)d_out);
}

// Round 11
// 1138.680 us; speedup vs baseline: 1.1004x; 1.1004x over previous
//
#include <hip/hip_runtime.h>
#include <cstdint>

#define NN 100000
#define NE 250000
#define MP 100096   // 391 * 256
#define MSTRIP 391
#define SCAN_B 256
#define NBLK ((NN + SCAN_B - 1) / SCAN_B)   // 391
#define NSLOT 32

using bf16x8 = __attribute__((ext_vector_type(8))) __bf16;
using f32x4v = __attribute__((ext_vector_type(4))) float;
using u16x8 = __attribute__((ext_vector_type(8))) unsigned short;

__device__ __forceinline__ unsigned short f2bf(float f) {
  union { float f; uint32_t u; } v; v.f = f;
  uint32_t r = v.u + 0x7FFFu + ((v.u >> 16) & 1u);
  return (unsigned short)(r >> 16);
}
__device__ __forceinline__ float bf2f(unsigned short u) {
  union { uint32_t u; float f; } v; v.u = ((uint32_t)u) << 16;
  return v.f;
}

__device__ __forceinline__ void ld_lds16(const void* g, void* l) {
  __builtin_amdgcn_global_load_lds(
      (const __attribute__((address_space(1))) void*)g,
      (__attribute__((address_space(3))) void*)l, 16, 0, 0);
}

// ---------------- prep (one dispatch): all-layer weights->bf16 transposed,
// padded combos/selfv, biases, padded embedding tables, zero BN state.
#define PER_L (640*320 + 384*640 + 12*304 + 304 + 640 + 384)          // 455536
#define GLOB_N (120*304 + 3*304 + 2*384 + 5*2*NSLOT*384)              // 529680
#define PREP_TOT (5 * PER_L + GLOB_N)
__global__ void prep_kernel(const float* __restrict__ W1, const float* __restrict__ W2,
                            const float* __restrict__ ee1, const float* __restrict__ ee2,
                            const float* __restrict__ b1, const float* __restrict__ b2,
                            const float* __restrict__ xe1, const float* __restrict__ xe2,
                            unsigned short* __restrict__ wt1, unsigned short* __restrict__ wt2,
                            float* __restrict__ combo, float* __restrict__ selfv,
                            float* __restrict__ b1p, float* __restrict__ b2p,
                            float* __restrict__ e1p, float* __restrict__ e2p,
                            float* __restrict__ bnAB, float* __restrict__ bnacc) {
  int i = blockIdx.x * 256 + threadIdx.x;
  if (i < 5 * PER_L) {
    int l = i / PER_L, j = i - l * PER_L;
    if (j < 640 * 320) {                     // wt1[l][n][k] = W1[l][k][n], pad 640x320
      int n = j / 320, k = j % 320;
      float v = (n < 600 && k < 300) ? W1[(size_t)l * 180000 + k * 600 + n] : 0.f;
      wt1[l * 204800 + j] = f2bf(v); return;
    }
    j -= 640 * 320;
    if (j < 384 * 640) {                     // wt2[l][n][k] = W2[l][k][n], pad 384x640
      int n = j / 640, k = j % 640;
      float v = (n < 300 && k < 600) ? W2[(size_t)l * 180000 + k * 300 + n] : 0.f;
      wt2[l * 245760 + j] = f2bf(v); return;
    }
    j -= 384 * 640;
    if (j < 12 * 304) {                      // combos [12][304], zero-padded
      int idx = j / 304, d = j % 304;
      int a = idx / 3, b = idx % 3;
      combo[l * 3648 + j] = (d < 300)
          ? ee1[l * 1800 + a * 300 + d] + ee2[l * 900 + b * 300 + d] : 0.f;
      return;
    }
    j -= 12 * 304;
    if (j < 304) {                           // selfv [304], zero-padded
      selfv[l * 304 + j] = (j < 300)
          ? ee1[l * 1800 + 4 * 300 + j] + ee2[l * 900 + j] : 0.f;
      return;
    }
    j -= 304;
    if (j < 640) { b1p[l * 640 + j] = (j < 600) ? b1[l * 600 + j] : 0.f; return; }
    j -= 640;
    b2p[l * 384 + j] = (j < 300) ? b2[l * 300 + j] : 0.f; return;
  }
  i -= 5 * PER_L;
  if (i < 120 * 304) {                       // padded x_emb1 [120][304]
    int n = i / 304, d = i % 304;
    e1p[i] = (d < 300) ? xe1[n * 300 + d] : 0.f; return;
  }
  i -= 120 * 304;
  if (i < 3 * 304) {                         // padded x_emb2 [3][304]
    int n = i / 304, d = i % 304;
    e2p[i] = (d < 300) ? xe2[n * 300 + d] : 0.f; return;
  }
  i -= 3 * 304;
  if (i < 2 * 384) { bnAB[i] = 0.f; return; }   // bnA|bnB zero (pads stay 0 forever)
  i -= 2 * 384;
  if (i < 5 * 2 * NSLOT * 384) bnacc[i] = 0.f;  // all BN accumulators
}

// ---------------- CSR build: degree histogram
__global__ void deg_kernel(const int* __restrict__ ei, int* __restrict__ deg) {
  int e = blockIdx.x * 256 + threadIdx.x;
  if (e >= NE) return;
  atomicAdd(&deg[ei[NE + e]], 1);
}

// ---------------- exclusive scan (3 kernels)
__global__ void scan1_kernel(const int* __restrict__ deg, int* __restrict__ off,
                             int* __restrict__ bsum) {
  __shared__ int tmp[SCAN_B];
  int b = blockIdx.x, t = threadIdx.x;
  int i = b * SCAN_B + t;
  int v = (i < NN) ? deg[i] : 0;
  tmp[t] = v;
  __syncthreads();
  for (int s = 1; s < SCAN_B; s <<= 1) {
    int a = (t >= s) ? tmp[t - s] : 0;
    __syncthreads();
    tmp[t] += a;
    __syncthreads();
  }
  if (i < NN) off[i] = tmp[t] - v;           // exclusive
  if (t == SCAN_B - 1) bsum[b] = tmp[t];
}
__global__ void scan2_kernel(int* __restrict__ bsum) {
  if (threadIdx.x == 0) {
    int acc = 0;
    for (int b = 0; b < NBLK; ++b) { int v = bsum[b]; bsum[b] = acc; acc += v; }
  }
}
__global__ void scan3_kernel(const int* __restrict__ bsum, int* __restrict__ off,
                             int* __restrict__ cursor) {
  int i = blockIdx.x * SCAN_B + threadIdx.x;
  if (i >= NN) return;
  int o = off[i] + bsum[blockIdx.x];
  off[i] = o;
  cursor[i] = o;
}

// ---------------- CSR fill: list[p] = src*16 + combo_idx
__global__ void fill_kernel(const int* __restrict__ ei, const int* __restrict__ ea,
                            int* __restrict__ cursor, int* __restrict__ list) {
  int e = blockIdx.x * 256 + threadIdx.x;
  if (e >= NE) return;
  int s = ei[e], d = ei[NE + e];
  int c = ea[2 * e] * 3 + ea[2 * e + 1];
  int p = atomicAdd(&cursor[d], 1);
  list[p] = s * 16 + c;
}

// ---------------- gather, 16B-granule: thread = (row, 16B chunk), 38 chunks/row.
// Fuses BN-apply + ReLU + aggregate + (1+eps)* + bf16 cast.
// MODE 0: source row = e1p[x0[s]] + e2p[x1[s]]       (layer 0, padded tables)
// MODE 1: source row = relu(bf16z[s]*bnA + bnB)      (layers 1..4; bnA/B pads = 0)
template <int MODE>
__global__ void gather_kernel(const unsigned short* __restrict__ zsrc,
                              const int* __restrict__ x, const float* __restrict__ e1p,
                              const float* __restrict__ e2p,
                              const float* __restrict__ bnA, const float* __restrict__ bnB,
                              const int* __restrict__ off, const int* __restrict__ deg,
                              const int* __restrict__ list,
                              const float* __restrict__ combo, const float* __restrict__ selfv,
                              const float* __restrict__ eps, int l,
                              unsigned short* __restrict__ abf) {
  int i = blockIdx.x * 256 + threadIdx.x;
  if (i >= NN * 38) return;
  int r = i / 38, qc = i % 38;
  const int cb = qc * 8;

  float4 a0, a1, b0, b1;
  if (MODE == 1) {
    a0 = *(const float4*)(bnA + cb); a1 = *(const float4*)(bnA + cb + 4);
    b0 = *(const float4*)(bnB + cb); b1 = *(const float4*)(bnB + cb + 4);
  }

  auto loadrow = [&](int s, float4& oL, float4& oH) {
    if (MODE == 0) {
      const float* p1 = e1p + (size_t)x[2 * s] * 304 + cb;
      const float* p2 = e2p + (size_t)x[2 * s + 1] * 304 + cb;
      float4 u0 = *(const float4*)p1, u1 = *(const float4*)(p1 + 4);
      float4 v0 = *(const float4*)p2, v1 = *(const float4*)(p2 + 4);
      oL.x = u0.x + v0.x; oL.y = u0.y + v0.y; oL.z = u0.z + v0.z; oL.w = u0.w + v0.w;
      oH.x = u1.x + v1.x; oH.y = u1.y + v1.y; oH.z = u1.z + v1.z; oH.w = u1.w + v1.w;
    } else {
      u16x8 zv = *reinterpret_cast<const u16x8*>(zsrc + (size_t)s * 384 + cb);
      oL.x = fmaxf(bf2f(zv[0]) * a0.x + b0.x, 0.f);
      oL.y = fmaxf(bf2f(zv[1]) * a0.y + b0.y, 0.f);
      oL.z = fmaxf(bf2f(zv[2]) * a0.z + b0.z, 0.f);
      oL.w = fmaxf(bf2f(zv[3]) * a0.w + b0.w, 0.f);
      oH.x = fmaxf(bf2f(zv[4]) * a1.x + b1.x, 0.f);
      oH.y = fmaxf(bf2f(zv[5]) * a1.y + b1.y, 0.f);
      oH.z = fmaxf(bf2f(zv[6]) * a1.z + b1.z, 0.f);
      oH.w = fmaxf(bf2f(zv[7]) * a1.w + b1.w, 0.f);
    }
  };

  float4 accL, accH;
  loadrow(r, accL, accH);
  {
    float4 s0 = *(const float4*)(selfv + cb), s1 = *(const float4*)(selfv + cb + 4);
    accL.x += s0.x; accL.y += s0.y; accL.z += s0.z; accL.w += s0.w;
    accH.x += s1.x; accH.y += s1.y; accH.z += s1.z; accH.w += s1.w;
  }

  int p0 = off[r], dn = deg[r];
  for (int p = 0; p < dn; ++p) {
    int pk = list[p0 + p];
    int s = pk >> 4, c = pk & 15;
    float4 hL, hH;
    loadrow(s, hL, hH);
    const float* cp = combo + c * 304 + cb;
    float4 c0 = *(const float4*)cp, c1 = *(const float4*)(cp + 4);
    accL.x += hL.x + c0.x; accL.y += hL.y + c0.y;
    accL.z += hL.z + c0.z; accL.w += hL.w + c0.w;
    accH.x += hH.x + c1.x; accH.y += hH.y + c1.y;
    accH.z += hH.z + c1.z; accH.w += hH.w + c1.w;
  }

  float sc = 1.f + eps[l];
  u16x8 o;
  o[0] = f2bf(accL.x * sc); o[1] = f2bf(accL.y * sc);
  o[2] = f2bf(accL.z * sc); o[3] = f2bf(accL.w * sc);
  o[4] = f2bf(accH.x * sc); o[5] = f2bf(accH.y * sc);
  o[6] = f2bf(accH.z * sc); o[7] = f2bf(accH.w * sc);
  *reinterpret_cast<u16x8*>(abf + (size_t)r * 320 + cb) = o;
}

// ---------------- bf16 MFMA GEMM (r8 structure): 8 waves, BM=256 x BN=128.
// Double-buffered LDS, counted-vmcnt prefetch, XCD remap (wid%8 = strip group).
// STATS: per-column sum/sumsq of output (rows < NN), slot-split 32x.
template <int LDA, int LDB, int NS, int NT, bool RELU, bool OBF16, bool STATS>
__global__ __launch_bounds__(512, 4) void gemm_kernel(
    const unsigned short* __restrict__ A, const unsigned short* __restrict__ B,
    const float* __restrict__ bias, void* __restrict__ C, int K,
    float* __restrict__ bnsum, float* __restrict__ bnsum2) {
  __shared__ unsigned short As[2][256 * 32];   // 2 x 16 KB
  __shared__ unsigned short Bs[2][128 * 32];   // 2 x 8 KB
  const int tid = threadIdx.x;
  const int lane = tid & 63;
  const int w = tid >> 6;            // 8 waves: wr = w>>1 (M), wc = w&1 (N)
  const int wr = w >> 1, wc = w & 1;
  const int l15 = lane & 15, l4 = lane >> 4;

  const int wid = blockIdx.x + gridDim.x * blockIdx.y;
  const int bmi = (wid & 7) + 8 * (wid / (8 * NT));
  const int ny  = (wid >> 3) % NT;
  if (bmi >= MSTRIP) return;
  const int bm = bmi * 256;
  const int bn = ny * 128;

  auto stage = [&](int buf, int kk) {
#pragma unroll
    for (int it = 0; it < 2; ++it) {
      int s = it * 512 + tid;
      int row = s >> 2, kbl = s & 3;
      int kbg = kbl ^ ((row >> 1) & 3);        // pre-swizzled global source
      ld_lds16(A + (size_t)(bm + row) * LDA + kk + kbg * 8, &As[buf][s * 8]);
    }
    {
      int s = tid;
      int row = s >> 2, kbl = s & 3;
      int kbg = kbl ^ ((row >> 1) & 3);
      ld_lds16(B + (size_t)(bn + row) * LDB + kk + kbg * 8, &Bs[buf][s * 8]);
    }
  };

  f32x4v acc[4][4] = {};
  const int nt = K / 32;

  stage(0, 0);
  for (int t = 0; t < nt; ++t) {
    const int cur = t & 1;
    if (t + 1 < nt) {
      stage(cur ^ 1, (t + 1) * 32);                     // prefetch next tile (3 loads)
      asm volatile("s_waitcnt vmcnt(3)" ::: "memory");  // my stage(t) loads landed
    } else {
      asm volatile("s_waitcnt vmcnt(0)" ::: "memory");
    }
    __builtin_amdgcn_s_barrier();                       // raw: no vmcnt(0) drain
    asm volatile("" ::: "memory");

    bf16x8 af[4], bfr[4];
#pragma unroll
    for (int mi = 0; mi < 4; ++mi) {
      int r = wr * 64 + mi * 16 + l15;
      int kb = l4 ^ ((r >> 1) & 3);            // swizzled read
      af[mi] = *reinterpret_cast<const bf16x8*>(&As[cur][(r * 4 + kb) * 8]);
    }
#pragma unroll
    for (int ni = 0; ni < 4; ++ni) {
      int r = wc * 64 + ni * 16 + l15;
      int kb = l4 ^ ((r >> 1) & 3);
      bfr[ni] = *reinterpret_cast<const bf16x8*>(&Bs[cur][(r * 4 + kb) * 8]);
    }
#pragma unroll
    for (int mi = 0; mi < 4; ++mi)
#pragma unroll
      for (int ni = 0; ni < 4; ++ni)
        acc[mi][ni] = __builtin_amdgcn_mfma_f32_16x16x32_bf16(af[mi], bfr[ni], acc[mi][ni], 0, 0, 0);

    __builtin_amdgcn_s_barrier();                       // buf free for re-stage
    asm volatile("" ::: "memory");
  }

  const int slot = wid & (NSLOT - 1);
#pragma unroll
  for (int ni = 0; ni < 4; ++ni) {
    int col = bn + wc * 64 + ni * 16 + l15;
    float bv = bias[col];
    float s = 0.f, s2 = 0.f;
#pragma unroll
    for (int mi = 0; mi < 4; ++mi) {
      int row0 = bm + wr * 64 + mi * 16 + (l4 << 2);
#pragma unroll
      for (int r = 0; r < 4; ++r) {
        float v = acc[mi][ni][r] + bv;
        if (RELU) v = fmaxf(v, 0.f);
        if (OBF16) ((unsigned short*)C)[(size_t)(row0 + r) * NS + col] = f2bf(v);
        else       ((float*)C)[(size_t)(row0 + r) * NS + col] = v;
        if (STATS && (row0 + r) < NN) { s += v; s2 += v * v; }
      }
    }
    if (STATS) {
      s  += __shfl_xor(s, 16);  s  += __shfl_xor(s, 32);
      s2 += __shfl_xor(s2, 16); s2 += __shfl_xor(s2, 32);
      if (l4 == 0) {
        atomicAdd(&bnsum[slot * 384 + col], s);
        atomicAdd(&bnsum2[slot * 384 + col], s2);
      }
    }
  }
}

__global__ void bnfinal_kernel(const float* __restrict__ bnsum, const float* __restrict__ bnsum2,
                               const float* __restrict__ gamma, const float* __restrict__ beta,
                               int l, float* __restrict__ Aout, float* __restrict__ Bout) {
  int c = threadIdx.x;
  if (c >= 300) return;
  float s = 0.f, s2 = 0.f;
  for (int k = 0; k < NSLOT; ++k) { s += bnsum[k * 384 + c]; s2 += bnsum2[k * 384 + c]; }
  float mean = s * (1.f / NN);
  float var = s2 * (1.f / NN) - mean * mean;
  var = fmaxf(var, 0.f);
  float inv = rsqrtf(var + 1e-5f);
  float a = gamma[l * 300 + c] * inv;
  Aout[c] = a;
  Bout[c] = beta[l * 300 + c] - mean * a;
}

// ---------------- final BN apply (layer 4, no ReLU): d_out[N][300] = bf2f(z)*A + B
__global__ void bnapply_kernel(const unsigned short* __restrict__ z, const float* __restrict__ Ain,
                               const float* __restrict__ Bin, float* __restrict__ out) {
  int i = blockIdx.x * 256 + threadIdx.x;
  if (i >= NN * 75) return;
  int r = i / 75, q = i % 75;
  ushort4 zv = ((const ushort4*)z)[(size_t)r * 96 + q];
  float4 a = ((const float4*)Ain)[q];
  float4 b = ((const float4*)Bin)[q];
  float4 o;
  o.x = bf2f(zv.x) * a.x + b.x; o.y = bf2f(zv.y) * a.y + b.y;
  o.z = bf2f(zv.z) * a.z + b.z; o.w = bf2f(zv.w) * a.w + b.w;
  ((float4*)out)[i] = o;
}

// ---------------- workspace layout (bytes; every increment is 16B-aligned)
constexpr size_t OFF_Z    = 0;                                    // z bf16 [MP][384]
constexpr size_t OFF_AB   = OFF_Z   + (size_t)MP * 384 * 2;       // abf16 [MP][320]
constexpr size_t OFF_Z1   = OFF_AB  + (size_t)MP * 320 * 2;       // z1 bf16 [MP][640]
constexpr size_t OFF_WT1  = OFF_Z1  + (size_t)MP * 640 * 2;       // wt1 [5][640*320]
constexpr size_t OFF_WT2  = OFF_WT1 + (size_t)5 * 204800 * 2;     // wt2 [5][384*640]
constexpr size_t OFF_CMB  = OFF_WT2 + (size_t)5 * 245760 * 2;     // combo f32 [5][12][304]
constexpr size_t OFF_SLF  = OFF_CMB + 5 * 3648 * 4;               // selfv f32 [5][304]
constexpr size_t OFF_E1P  = OFF_SLF + 5 * 304 * 4;                // e1p f32 [120][304]
constexpr size_t OFF_E2P  = OFF_E1P + 120 * 304 * 4;              // e2p f32 [3][304]
constexpr size_t OFF_B1   = OFF_E2P + 3 * 304 * 4;                // b1p f32 [5][640]
constexpr size_t OFF_B2   = OFF_B1  + 5 * 640 * 4;                // b2p f32 [5][384]
constexpr size_t OFF_S1   = OFF_B2  + 5 * 384 * 4;                // bnsum  [5][32][384]
constexpr size_t OFF_S2   = OFF_S1  + (size_t)5 * NSLOT * 384 * 4;// bnsum2 (contiguous)
constexpr size_t OFF_BA   = OFF_S2  + (size_t)5 * NSLOT * 384 * 4;// bnA f32 [384]
constexpr size_t OFF_BB   = OFF_BA + 1536;                        // bnB f32 [384]
constexpr size_t OFF_DEG  = OFF_BB + 1536;              // int[NN]
constexpr size_t OFF_OFFS = OFF_DEG + 400384;           // int[NN]
constexpr size_t OFF_CUR  = OFF_OFFS + 400384;          // int[NN]
constexpr size_t OFF_BS   = OFF_CUR + 400384;           // int[NBLK]
constexpr size_t OFF_LIST = OFF_BS + 2048;              // int[NE]

extern "C" void kernel_launch(void* const* d_in, const int* in_sizes, int n_in,
                              void* d_out, int out_size, void* d_ws, size_t ws_size,
                              hipStream_t stream) {
  const int*   x     = (const int*)d_in[0];
  const int*   ei    = (const int*)d_in[1];
  const int*   ea    = (const int*)d_in[2];
  const float* xe1   = (const float*)d_in[3];
  const float* xe2   = (const float*)d_in[4];
  const float* ee1   = (const float*)d_in[5];
  const float* ee2   = (const float*)d_in[6];
  const float* W1    = (const float*)d_in[7];
  const float* b1    = (const float*)d_in[8];
  const float* W2    = (const float*)d_in[9];
  const float* b2    = (const float*)d_in[10];
  const float* eps   = (const float*)d_in[11];
  const float* gamma = (const float*)d_in[12];
  const float* beta  = (const float*)d_in[13];

  char* ws = (char*)d_ws;
  unsigned short* zf    = (unsigned short*)(ws + OFF_Z);
  unsigned short* abf   = (unsigned short*)(ws + OFF_AB);
  unsigned short* z1    = (unsigned short*)(ws + OFF_Z1);
  unsigned short* wt1   = (unsigned short*)(ws + OFF_WT1);
  unsigned short* wt2   = (unsigned short*)(ws + OFF_WT2);
  float*          combo = (float*)(ws + OFF_CMB);
  float*          selfv = (float*)(ws + OFF_SLF);
  float*          e1p   = (float*)(ws + OFF_E1P);
  float*          e2p   = (float*)(ws + OFF_E2P);
  float*          b1p   = (float*)(ws + OFF_B1);
  float*          b2p   = (float*)(ws + OFF_B2);
  float*          bns   = (float*)(ws + OFF_S1);
  float*          bns2  = (float*)(ws + OFF_S2);
  float*          bnA   = (float*)(ws + OFF_BA);
  float*          bnB   = (float*)(ws + OFF_BB);
  int*            deg   = (int*)(ws + OFF_DEG);
  int*            offs  = (int*)(ws + OFF_OFFS);
  int*            cur   = (int*)(ws + OFF_CUR);
  int*            bsum  = (int*)(ws + OFF_BS);
  int*            list  = (int*)(ws + OFF_LIST);

  const int g_g    = (NN * 38 + 255) / 256;   // gather: 16B chunks
  const int g_ew   = (NN * 75 + 255) / 256;   // bnapply: float4 chunks
  const int g_e    = (NE + 255) / 256;
  const int g_prep = (PREP_TOT + 255) / 256;
  const int GX     = 392;   // 49 groups of 8 row-strips (1 idle strip: 391)

  // one-time per launch: zero abf (cols 304..319 stay 0 across layers), deg
  hipMemsetAsync(abf, 0, (size_t)MP * 320 * 2, stream);
  hipMemsetAsync(deg, 0, NN * 4, stream);

  // all-layer prep (weights, combos, selfv, biases, padded emb tables, BN zeroing)
  prep_kernel<<<g_prep, 256, 0, stream>>>(W1, W2, ee1, ee2, b1, b2, xe1, xe2,
                                          wt1, wt2, combo, selfv, b1p, b2p,
                                          e1p, e2p, bnA, bns);

  // CSR build (graph static across layers)
  deg_kernel<<<g_e, 256, 0, stream>>>(ei, deg);
  scan1_kernel<<<NBLK, SCAN_B, 0, stream>>>(deg, offs, bsum);
  scan2_kernel<<<1, 64, 0, stream>>>(bsum);
  scan3_kernel<<<NBLK, SCAN_B, 0, stream>>>(bsum, offs, cur);
  fill_kernel<<<g_e, 256, 0, stream>>>(ei, ea, cur, list);

  for (int l = 0; l < 5; ++l) {
    float* bns_l  = bns  + (size_t)l * NSLOT * 384;
    float* bns2_l = bns2 + (size_t)l * NSLOT * 384;
    if (l == 0)
      gather_kernel<0><<<g_g, 256, 0, stream>>>(zf, x, e1p, e2p, bnA, bnB,
                                                offs, deg, list, combo + l * 3648,
                                                selfv + l * 304, eps, l, abf);
    else
      gather_kernel<1><<<g_g, 256, 0, stream>>>(zf, x, e1p, e2p, bnA, bnB,
                                                offs, deg, list, combo + l * 3648,
                                                selfv + l * 304, eps, l, abf);
    gemm_kernel<320, 320, 640, 5, true, true, false><<<dim3(GX, 5), 512, 0, stream>>>(
        abf, wt1 + (size_t)l * 204800, b1p + l * 640, (void*)z1, 320, bns_l, bns2_l);
    gemm_kernel<640, 640, 384, 3, false, true, true><<<dim3(GX, 3), 512, 0, stream>>>(
        z1, wt2 + (size_t)l * 245760, b2p + l * 384, (void*)zf, 640, bns_l, bns2_l);
    bnfinal_kernel<<<1, 384, 0, stream>>>(bns_l, bns2_l, gamma, beta, l, bnA, bnB);
  }
  bnapply_kernel<<<g_ew, 256, 0, stream>>>(zf, bnA, bnB, (float*)d_out);
}

// Round 12
// 1059.885 us; speedup vs baseline: 1.1822x; 1.0743x over previous
//
#include <hip/hip_runtime.h>
#include <cstdint>

#define NN 100000
#define NE 250000
#define MP 100096   // 391 * 256
#define MSTRIP 391
#define SCAN_B 256
#define NBLK ((NN + SCAN_B - 1) / SCAN_B)   // 391
#define NSLOT 32
#define N1 608      // z1 real-ish width (600 live + 8 zero), 19*32
#define NZ 320      // z width (300 live + 20 zero)

using bf16x8 = __attribute__((ext_vector_type(8))) __bf16;
using f32x4v = __attribute__((ext_vector_type(4))) float;
using u16x8 = __attribute__((ext_vector_type(8))) unsigned short;

__device__ __forceinline__ unsigned short f2bf(float f) {
  union { float f; uint32_t u; } v; v.f = f;
  uint32_t r = v.u + 0x7FFFu + ((v.u >> 16) & 1u);
  return (unsigned short)(r >> 16);
}
__device__ __forceinline__ float bf2f(unsigned short u) {
  union { uint32_t u; float f; } v; v.u = ((uint32_t)u) << 16;
  return v.f;
}

__device__ __forceinline__ void ld_lds16(const void* g, void* l) {
  __builtin_amdgcn_global_load_lds(
      (const __attribute__((address_space(1))) void*)g,
      (__attribute__((address_space(3))) void*)l, 16, 0, 0);
}

// ---------------- prep (one dispatch): all-layer weights->bf16 transposed,
// padded combos/selfv, biases, padded embedding tables, zero BN state.
#define PER_L (640*320 + 384*640 + 12*304 + 304 + 640 + 384)          // 455536
#define GLOB_N (120*304 + 3*304 + 2*384 + 5*2*NSLOT*384)              // 529680
#define PREP_TOT (5 * PER_L + GLOB_N)
__global__ void prep_kernel(const float* __restrict__ W1, const float* __restrict__ W2,
                            const float* __restrict__ ee1, const float* __restrict__ ee2,
                            const float* __restrict__ b1, const float* __restrict__ b2,
                            const float* __restrict__ xe1, const float* __restrict__ xe2,
                            unsigned short* __restrict__ wt1, unsigned short* __restrict__ wt2,
                            float* __restrict__ combo, float* __restrict__ selfv,
                            float* __restrict__ b1p, float* __restrict__ b2p,
                            float* __restrict__ e1p, float* __restrict__ e2p,
                            float* __restrict__ bnAB, float* __restrict__ bnacc) {
  int i = blockIdx.x * 256 + threadIdx.x;
  if (i < 5 * PER_L) {
    int l = i / PER_L, j = i - l * PER_L;
    if (j < 640 * 320) {                     // wt1[l][n][k] = W1[l][k][n], pad 640x320
      int n = j / 320, k = j % 320;
      float v = (n < 600 && k < 300) ? W1[(size_t)l * 180000 + k * 600 + n] : 0.f;
      wt1[l * 204800 + j] = f2bf(v); return;
    }
    j -= 640 * 320;
    if (j < 384 * 640) {                     // wt2[l][n][k] = W2[l][k][n], pad 384x640
      int n = j / 640, k = j % 640;
      float v = (n < 300 && k < 600) ? W2[(size_t)l * 180000 + k * 300 + n] : 0.f;
      wt2[l * 245760 + j] = f2bf(v); return;
    }
    j -= 384 * 640;
    if (j < 12 * 304) {                      // combos [12][304], zero-padded
      int idx = j / 304, d = j % 304;
      int a = idx / 3, b = idx % 3;
      combo[l * 3648 + j] = (d < 300)
          ? ee1[l * 1800 + a * 300 + d] + ee2[l * 900 + b * 300 + d] : 0.f;
      return;
    }
    j -= 12 * 304;
    if (j < 304) {                           // selfv [304], zero-padded
      selfv[l * 304 + j] = (j < 300)
          ? ee1[l * 1800 + 4 * 300 + j] + ee2[l * 900 + j] : 0.f;
      return;
    }
    j -= 304;
    if (j < 640) { b1p[l * 640 + j] = (j < 600) ? b1[l * 600 + j] : 0.f; return; }
    j -= 640;
    b2p[l * 384 + j] = (j < 300) ? b2[l * 300 + j] : 0.f; return;
  }
  i -= 5 * PER_L;
  if (i < 120 * 304) {                       // padded x_emb1 [120][304]
    int n = i / 304, d = i % 304;
    e1p[i] = (d < 300) ? xe1[n * 300 + d] : 0.f; return;
  }
  i -= 120 * 304;
  if (i < 3 * 304) {                         // padded x_emb2 [3][304]
    int n = i / 304, d = i % 304;
    e2p[i] = (d < 300) ? xe2[n * 300 + d] : 0.f; return;
  }
  i -= 3 * 304;
  if (i < 2 * 384) { bnAB[i] = 0.f; return; }   // bnA|bnB zero (pads stay 0 forever)
  i -= 2 * 384;
  if (i < 5 * 2 * NSLOT * 384) bnacc[i] = 0.f;  // all BN accumulators
}

// ---------------- CSR build: degree histogram
__global__ void deg_kernel(const int* __restrict__ ei, int* __restrict__ deg) {
  int e = blockIdx.x * 256 + threadIdx.x;
  if (e >= NE) return;
  atomicAdd(&deg[ei[NE + e]], 1);
}

// ---------------- exclusive scan (3 kernels)
__global__ void scan1_kernel(const int* __restrict__ deg, int* __restrict__ off,
                             int* __restrict__ bsum) {
  __shared__ int tmp[SCAN_B];
  int b = blockIdx.x, t = threadIdx.x;
  int i = b * SCAN_B + t;
  int v = (i < NN) ? deg[i] : 0;
  tmp[t] = v;
  __syncthreads();
  for (int s = 1; s < SCAN_B; s <<= 1) {
    int a = (t >= s) ? tmp[t - s] : 0;
    __syncthreads();
    tmp[t] += a;
    __syncthreads();
  }
  if (i < NN) off[i] = tmp[t] - v;           // exclusive
  if (t == SCAN_B - 1) bsum[b] = tmp[t];
}
__global__ void scan2_kernel(int* __restrict__ bsum) {
  if (threadIdx.x == 0) {
    int acc = 0;
    for (int b = 0; b < NBLK; ++b) { int v = bsum[b]; bsum[b] = acc; acc += v; }
  }
}
__global__ void scan3_kernel(const int* __restrict__ bsum, int* __restrict__ off,
                             int* __restrict__ cursor) {
  int i = blockIdx.x * SCAN_B + threadIdx.x;
  if (i >= NN) return;
  int o = off[i] + bsum[blockIdx.x];
  off[i] = o;
  cursor[i] = o;
}

// ---------------- CSR fill: list[p] = src*16 + combo_idx
__global__ void fill_kernel(const int* __restrict__ ei, const int* __restrict__ ea,
                            int* __restrict__ cursor, int* __restrict__ list) {
  int e = blockIdx.x * 256 + threadIdx.x;
  if (e >= NE) return;
  int s = ei[e], d = ei[NE + e];
  int c = ea[2 * e] * 3 + ea[2 * e + 1];
  int p = atomicAdd(&cursor[d], 1);
  list[p] = s * 16 + c;
}

// ---------------- gather, 16B-granule: thread = (row, 16B chunk), 38 chunks/row.
// MODE 0: source row = e1p[x0[s]] + e2p[x1[s]]       (layer 0, padded tables)
// MODE 1: source row = relu(bf16z[s]*bnA + bnB)      (layers 1..4; z stride NZ)
template <int MODE>
__global__ void gather_kernel(const unsigned short* __restrict__ zsrc,
                              const int* __restrict__ x, const float* __restrict__ e1p,
                              const float* __restrict__ e2p,
                              const float* __restrict__ bnA, const float* __restrict__ bnB,
                              const int* __restrict__ off, const int* __restrict__ deg,
                              const int* __restrict__ list,
                              const float* __restrict__ combo, const float* __restrict__ selfv,
                              const float* __restrict__ eps, int l,
                              unsigned short* __restrict__ abf) {
  int i = blockIdx.x * 256 + threadIdx.x;
  if (i >= NN * 38) return;
  int r = i / 38, qc = i % 38;
  const int cb = qc * 8;

  float4 a0, a1, b0, b1;
  if (MODE == 1) {
    a0 = *(const float4*)(bnA + cb); a1 = *(const float4*)(bnA + cb + 4);
    b0 = *(const float4*)(bnB + cb); b1 = *(const float4*)(bnB + cb + 4);
  }

  auto loadrow = [&](int s, float4& oL, float4& oH) {
    if (MODE == 0) {
      const float* p1 = e1p + (size_t)x[2 * s] * 304 + cb;
      const float* p2 = e2p + (size_t)x[2 * s + 1] * 304 + cb;
      float4 u0 = *(const float4*)p1, u1 = *(const float4*)(p1 + 4);
      float4 v0 = *(const float4*)p2, v1 = *(const float4*)(p2 + 4);
      oL.x = u0.x + v0.x; oL.y = u0.y + v0.y; oL.z = u0.z + v0.z; oL.w = u0.w + v0.w;
      oH.x = u1.x + v1.x; oH.y = u1.y + v1.y; oH.z = u1.z + v1.z; oH.w = u1.w + v1.w;
    } else {
      u16x8 zv = *reinterpret_cast<const u16x8*>(zsrc + (size_t)s * NZ + cb);
      oL.x = fmaxf(bf2f(zv[0]) * a0.x + b0.x, 0.f);
      oL.y = fmaxf(bf2f(zv[1]) * a0.y + b0.y, 0.f);
      oL.z = fmaxf(bf2f(zv[2]) * a0.z + b0.z, 0.f);
      oL.w = fmaxf(bf2f(zv[3]) * a0.w + b0.w, 0.f);
      oH.x = fmaxf(bf2f(zv[4]) * a1.x + b1.x, 0.f);
      oH.y = fmaxf(bf2f(zv[5]) * a1.y + b1.y, 0.f);
      oH.z = fmaxf(bf2f(zv[6]) * a1.z + b1.z, 0.f);
      oH.w = fmaxf(bf2f(zv[7]) * a1.w + b1.w, 0.f);
    }
  };

  float4 accL, accH;
  loadrow(r, accL, accH);
  {
    float4 s0 = *(const float4*)(selfv + cb), s1 = *(const float4*)(selfv + cb + 4);
    accL.x += s0.x; accL.y += s0.y; accL.z += s0.z; accL.w += s0.w;
    accH.x += s1.x; accH.y += s1.y; accH.z += s1.z; accH.w += s1.w;
  }

  int p0 = off[r], dn = deg[r];
  for (int p = 0; p < dn; ++p) {
    int pk = list[p0 + p];
    int s = pk >> 4, c = pk & 15;
    float4 hL, hH;
    loadrow(s, hL, hH);
    const float* cp = combo + c * 304 + cb;
    float4 c0 = *(const float4*)cp, c1 = *(const float4*)(cp + 4);
    accL.x += hL.x + c0.x; accL.y += hL.y + c0.y;
    accL.z += hL.z + c0.z; accL.w += hL.w + c0.w;
    accH.x += hH.x + c1.x; accH.y += hH.y + c1.y;
    accH.z += hH.z + c1.z; accH.w += hH.w + c1.w;
  }

  float sc = 1.f + eps[l];
  u16x8 o;
  o[0] = f2bf(accL.x * sc); o[1] = f2bf(accL.y * sc);
  o[2] = f2bf(accL.z * sc); o[3] = f2bf(accL.w * sc);
  o[4] = f2bf(accH.x * sc); o[5] = f2bf(accH.y * sc);
  o[6] = f2bf(accH.z * sc); o[7] = f2bf(accH.w * sc);
  *reinterpret_cast<u16x8*>(abf + (size_t)r * 320 + cb) = o;
}

// ---------------- bf16 MFMA GEMM (r8 structure): 8 waves, BM=256 x BN=128.
// Double-buffered LDS, counted-vmcnt prefetch, XCD remap (wid%8 = strip group).
// NSTORE: only cols < NSTORE are stored / counted (pad cols are provably zero).
// STATS: per-column sum/sumsq of output (rows < NN), slot-split 32x.
template <int LDA, int LDB, int NS, int NSTORE, int NT, bool RELU, bool OBF16, bool STATS>
__global__ __launch_bounds__(512, 4) void gemm_kernel(
    const unsigned short* __restrict__ A, const unsigned short* __restrict__ B,
    const float* __restrict__ bias, void* __restrict__ C, int K,
    float* __restrict__ bnsum, float* __restrict__ bnsum2) {
  __shared__ unsigned short As[2][256 * 32];   // 2 x 16 KB
  __shared__ unsigned short Bs[2][128 * 32];   // 2 x 8 KB
  const int tid = threadIdx.x;
  const int lane = tid & 63;
  const int w = tid >> 6;            // 8 waves: wr = w>>1 (M), wc = w&1 (N)
  const int wr = w >> 1, wc = w & 1;
  const int l15 = lane & 15, l4 = lane >> 4;

  const int wid = blockIdx.x + gridDim.x * blockIdx.y;
  const int bmi = (wid & 7) + 8 * (wid / (8 * NT));
  const int ny  = (wid >> 3) % NT;
  if (bmi >= MSTRIP) return;
  const int bm = bmi * 256;
  const int bn = ny * 128;

  auto stage = [&](int buf, int kk) {
#pragma unroll
    for (int it = 0; it < 2; ++it) {
      int s = it * 512 + tid;
      int row = s >> 2, kbl = s & 3;
      int kbg = kbl ^ ((row >> 1) & 3);        // pre-swizzled global source
      ld_lds16(A + (size_t)(bm + row) * LDA + kk + kbg * 8, &As[buf][s * 8]);
    }
    {
      int s = tid;
      int row = s >> 2, kbl = s & 3;
      int kbg = kbl ^ ((row >> 1) & 3);
      ld_lds16(B + (size_t)(bn + row) * LDB + kk + kbg * 8, &Bs[buf][s * 8]);
    }
  };

  f32x4v acc[4][4] = {};
  const int nt = K / 32;

  stage(0, 0);
  for (int t = 0; t < nt; ++t) {
    const int cur = t & 1;
    if (t + 1 < nt) {
      stage(cur ^ 1, (t + 1) * 32);                     // prefetch next tile (3 loads)
      asm volatile("s_waitcnt vmcnt(3)" ::: "memory");  // my stage(t) loads landed
    } else {
      asm volatile("s_waitcnt vmcnt(0)" ::: "memory");
    }
    __builtin_amdgcn_s_barrier();                       // raw: no vmcnt(0) drain
    asm volatile("" ::: "memory");

    bf16x8 af[4], bfr[4];
#pragma unroll
    for (int mi = 0; mi < 4; ++mi) {
      int r = wr * 64 + mi * 16 + l15;
      int kb = l4 ^ ((r >> 1) & 3);            // swizzled read
      af[mi] = *reinterpret_cast<const bf16x8*>(&As[cur][(r * 4 + kb) * 8]);
    }
#pragma unroll
    for (int ni = 0; ni < 4; ++ni) {
      int r = wc * 64 + ni * 16 + l15;
      int kb = l4 ^ ((r >> 1) & 3);
      bfr[ni] = *reinterpret_cast<const bf16x8*>(&Bs[cur][(r * 4 + kb) * 8]);
    }
#pragma unroll
    for (int mi = 0; mi < 4; ++mi)
#pragma unroll
      for (int ni = 0; ni < 4; ++ni)
        acc[mi][ni] = __builtin_amdgcn_mfma_f32_16x16x32_bf16(af[mi], bfr[ni], acc[mi][ni], 0, 0, 0);

    __builtin_amdgcn_s_barrier();                       // buf free for re-stage
    asm volatile("" ::: "memory");
  }

  const int slot = wid & (NSLOT - 1);
#pragma unroll
  for (int ni = 0; ni < 4; ++ni) {
    int col = bn + wc * 64 + ni * 16 + l15;
    if (col >= NSTORE) continue;               // pad cols: provably zero, skip
    float bv = bias[col];
    float s = 0.f, s2 = 0.f;
#pragma unroll
    for (int mi = 0; mi < 4; ++mi) {
      int row0 = bm + wr * 64 + mi * 16 + (l4 << 2);
#pragma unroll
      for (int r = 0; r < 4; ++r) {
        float v = acc[mi][ni][r] + bv;
        if (RELU) v = fmaxf(v, 0.f);
        if (OBF16) ((unsigned short*)C)[(size_t)(row0 + r) * NS + col] = f2bf(v);
        else       ((float*)C)[(size_t)(row0 + r) * NS + col] = v;
        if (STATS && (row0 + r) < NN) { s += v; s2 += v * v; }
      }
    }
    if (STATS) {
      s  += __shfl_xor(s, 16);  s  += __shfl_xor(s, 32);
      s2 += __shfl_xor(s2, 16); s2 += __shfl_xor(s2, 32);
      if (l4 == 0) {
        atomicAdd(&bnsum[slot * 384 + col], s);
        atomicAdd(&bnsum2[slot * 384 + col], s2);
      }
    }
  }
}

__global__ void bnfinal_kernel(const float* __restrict__ bnsum, const float* __restrict__ bnsum2,
                               const float* __restrict__ gamma, const float* __restrict__ beta,
                               int l, float* __restrict__ Aout, float* __restrict__ Bout) {
  int c = threadIdx.x;
  if (c >= 300) return;
  float s = 0.f, s2 = 0.f;
  for (int k = 0; k < NSLOT; ++k) { s += bnsum[k * 384 + c]; s2 += bnsum2[k * 384 + c]; }
  float mean = s * (1.f / NN);
  float var = s2 * (1.f / NN) - mean * mean;
  var = fmaxf(var, 0.f);
  float inv = rsqrtf(var + 1e-5f);
  float a = gamma[l * 300 + c] * inv;
  Aout[c] = a;
  Bout[c] = beta[l * 300 + c] - mean * a;
}

// ---------------- final BN apply (layer 4, no ReLU): d_out[N][300] = bf2f(z)*A + B
__global__ void bnapply_kernel(const unsigned short* __restrict__ z, const float* __restrict__ Ain,
                               const float* __restrict__ Bin, float* __restrict__ out) {
  int i = blockIdx.x * 256 + threadIdx.x;
  if (i >= NN * 75) return;
  int r = i / 75, q = i % 75;
  ushort4 zv = ((const ushort4*)z)[(size_t)r * (NZ / 4) + q];
  float4 a = ((const float4*)Ain)[q];
  float4 b = ((const float4*)Bin)[q];
  float4 o;
  o.x = bf2f(zv.x) * a.x + b.x; o.y = bf2f(zv.y) * a.y + b.y;
  o.z = bf2f(zv.z) * a.z + b.z; o.w = bf2f(zv.w) * a.w + b.w;
  ((float4*)out)[i] = o;
}

// ---------------- workspace layout (bytes; every increment is 16B-aligned)
constexpr size_t OFF_Z    = 0;                                    // z bf16 [MP][320]
constexpr size_t OFF_AB   = OFF_Z   + (size_t)MP * NZ * 2;        // abf16 [MP][320]
constexpr size_t OFF_Z1   = OFF_AB  + (size_t)MP * 320 * 2;       // z1 bf16 [MP][608]
constexpr size_t OFF_WT1  = OFF_Z1  + (size_t)MP * N1 * 2;        // wt1 [5][640*320]
constexpr size_t OFF_WT2  = OFF_WT1 + (size_t)5 * 204800 * 2;     // wt2 [5][384*640]
constexpr size_t OFF_CMB  = OFF_WT2 + (size_t)5 * 245760 * 2;     // combo f32 [5][12][304]
constexpr size_t OFF_SLF  = OFF_CMB + 5 * 3648 * 4;               // selfv f32 [5][304]
constexpr size_t OFF_E1P  = OFF_SLF + 5 * 304 * 4;                // e1p f32 [120][304]
constexpr size_t OFF_E2P  = OFF_E1P + 120 * 304 * 4;              // e2p f32 [3][304]
constexpr size_t OFF_B1   = OFF_E2P + 3 * 304 * 4;                // b1p f32 [5][640]
constexpr size_t OFF_B2   = OFF_B1  + 5 * 640 * 4;                // b2p f32 [5][384]
constexpr size_t OFF_S1   = OFF_B2  + 5 * 384 * 4;                // bnsum  [5][32][384]
constexpr size_t OFF_S2   = OFF_S1  + (size_t)5 * NSLOT * 384 * 4;// bnsum2 (contiguous)
constexpr size_t OFF_BA   = OFF_S2  + (size_t)5 * NSLOT * 384 * 4;// bnA f32 [384]
constexpr size_t OFF_BB   = OFF_BA + 1536;                        // bnB f32 [384]
constexpr size_t OFF_DEG  = OFF_BB + 1536;              // int[NN]
constexpr size_t OFF_OFFS = OFF_DEG + 400384;           // int[NN]
constexpr size_t OFF_CUR  = OFF_OFFS + 400384;          // int[NN]
constexpr size_t OFF_BS   = OFF_CUR + 400384;           // int[NBLK]
constexpr size_t OFF_LIST = OFF_BS + 2048;              // int[NE]

extern "C" void kernel_launch(void* const* d_in, const int* in_sizes, int n_in,
                              void* d_out, int out_size, void* d_ws, size_t ws_size,
                              hipStream_t stream) {
  const int*   x     = (const int*)d_in[0];
  const int*   ei    = (const int*)d_in[1];
  const int*   ea    = (const int*)d_in[2];
  const float* xe1   = (const float*)d_in[3];
  const float* xe2   = (const float*)d_in[4];
  const float* ee1   = (const float*)d_in[5];
  const float* ee2   = (const float*)d_in[6];
  const float* W1    = (const float*)d_in[7];
  const float* b1    = (const float*)d_in[8];
  const float* W2    = (const float*)d_in[9];
  const float* b2    = (const float*)d_in[10];
  const float* eps   = (const float*)d_in[11];
  const float* gamma = (const float*)d_in[12];
  const float* beta  = (const float*)d_in[13];

  char* ws = (char*)d_ws;
  unsigned short* zf    = (unsigned short*)(ws + OFF_Z);
  unsigned short* abf   = (unsigned short*)(ws + OFF_AB);
  unsigned short* z1    = (unsigned short*)(ws + OFF_Z1);
  unsigned short* wt1   = (unsigned short*)(ws + OFF_WT1);
  unsigned short* wt2   = (unsigned short*)(ws + OFF_WT2);
  float*          combo = (float*)(ws + OFF_CMB);
  float*          selfv = (float*)(ws + OFF_SLF);
  float*          e1p   = (float*)(ws + OFF_E1P);
  float*          e2p   = (float*)(ws + OFF_E2P);
  float*          b1p   = (float*)(ws + OFF_B1);
  float*          b2p   = (float*)(ws + OFF_B2);
  float*          bns   = (float*)(ws + OFF_S1);
  float*          bns2  = (float*)(ws + OFF_S2);
  float*          bnA   = (float*)(ws + OFF_BA);
  float*          bnB   = (float*)(ws + OFF_BB);
  int*            deg   = (int*)(ws + OFF_DEG);
  int*            offs  = (int*)(ws + OFF_OFFS);
  int*            cur   = (int*)(ws + OFF_CUR);
  int*            bsum  = (int*)(ws + OFF_BS);
  int*            list  = (int*)(ws + OFF_LIST);

  const int g_g    = (NN * 38 + 255) / 256;   // gather: 16B chunks
  const int g_ew   = (NN * 75 + 255) / 256;   // bnapply: float4 chunks
  const int g_e    = (NE + 255) / 256;
  const int g_prep = (PREP_TOT + 255) / 256;
  const int GX     = 392;   // 49 groups of 8 row-strips (1 idle strip: 391)

  // one-time per launch: zero abf (cols 304..319 stay 0 across layers), deg
  hipMemsetAsync(abf, 0, (size_t)MP * 320 * 2, stream);
  hipMemsetAsync(deg, 0, NN * 4, stream);

  // all-layer prep (weights, combos, selfv, biases, padded emb tables, BN zeroing)
  prep_kernel<<<g_prep, 256, 0, stream>>>(W1, W2, ee1, ee2, b1, b2, xe1, xe2,
                                          wt1, wt2, combo, selfv, b1p, b2p,
                                          e1p, e2p, bnA, bns);

  // CSR build (graph static across layers)
  deg_kernel<<<g_e, 256, 0, stream>>>(ei, deg);
  scan1_kernel<<<NBLK, SCAN_B, 0, stream>>>(deg, offs, bsum);
  scan2_kernel<<<1, 64, 0, stream>>>(bsum);
  scan3_kernel<<<NBLK, SCAN_B, 0, stream>>>(bsum, offs, cur);
  fill_kernel<<<g_e, 256, 0, stream>>>(ei, ea, cur, list);

  for (int l = 0; l < 5; ++l) {
    float* bns_l  = bns  + (size_t)l * NSLOT * 384;
    float* bns2_l = bns2 + (size_t)l * NSLOT * 384;
    if (l == 0)
      gather_kernel<0><<<g_g, 256, 0, stream>>>(zf, x, e1p, e2p, bnA, bnB,
                                                offs, deg, list, combo + l * 3648,
                                                selfv + l * 304, eps, l, abf);
    else
      gather_kernel<1><<<g_g, 256, 0, stream>>>(zf, x, e1p, e2p, bnA, bnB,
                                                offs, deg, list, combo + l * 3648,
                                                selfv + l * 304, eps, l, abf);
    // GEMM1: [MP][320] @ wt1^T -> z1 [MP][608] (cols 608..639 are zero, skipped)
    gemm_kernel<320, 320, N1, N1, 5, true, true, false><<<dim3(GX, 5), 512, 0, stream>>>(
        abf, wt1 + (size_t)l * 204800, b1p + l * 640, (void*)z1, 320, bns_l, bns2_l);
    // GEMM2: z1 [MP][608] @ wt2^T (K=608) -> z [MP][320] (cols 320..383 skipped)
    gemm_kernel<N1, 640, NZ, NZ, 3, false, true, true><<<dim3(GX, 3), 512, 0, stream>>>(
        z1, wt2 + (size_t)l * 245760, b2p + l * 384, (void*)zf, N1, bns_l, bns2_l);
    bnfinal_kernel<<<1, 384, 0, stream>>>(bns_l, bns2_l, gamma, beta, l, bnA, bnB);
  }
  bnapply_kernel<<<g_ew, 256, 0, stream>>>(zf, bnA, bnB, (float*)d_out);
}

// Round 13
// 1044.639 us; speedup vs baseline: 1.1995x; 1.0146x over previous
//
#include <hip/hip_runtime.h>
#include <cstdint>

#define NN 100000
#define NE 250000
#define MP 100096   // 391 * 256
#define MSTRIP 391
#define SCAN_B 256
#define NBLK ((NN + SCAN_B - 1) / SCAN_B)   // 391
#define NSLOT 32
#define N1 608      // z1 width (600 live + 8 zero), 19*32
#define NZ 320      // z width (300 live + 20 zero)

using bf16x8 = __attribute__((ext_vector_type(8))) __bf16;
using f32x4v = __attribute__((ext_vector_type(4))) float;
using u16x8 = __attribute__((ext_vector_type(8))) unsigned short;

__device__ __forceinline__ unsigned short f2bf(float f) {
  union { float f; uint32_t u; } v; v.f = f;
  uint32_t r = v.u + 0x7FFFu + ((v.u >> 16) & 1u);
  return (unsigned short)(r >> 16);
}
__device__ __forceinline__ float bf2f(unsigned short u) {
  union { uint32_t u; float f; } v; v.u = ((uint32_t)u) << 16;
  return v.f;
}

__device__ __forceinline__ void ld_lds16(const void* g, void* l) {
  __builtin_amdgcn_global_load_lds(
      (const __attribute__((address_space(1))) void*)g,
      (__attribute__((address_space(3))) void*)l, 16, 0, 0);
}

// ---------------- prep (one dispatch): all-layer weights->bf16 transposed,
// padded combos/selfv, biases, padded embedding tables, zero BN state.
#define PER_L (640*320 + 384*640 + 12*304 + 304 + 640 + 384)          // 455536
#define GLOB_N (120*304 + 3*304 + 2*384 + 5*2*NSLOT*384)              // 529680
#define PREP_TOT (5 * PER_L + GLOB_N)
__global__ void prep_kernel(const float* __restrict__ W1, const float* __restrict__ W2,
                            const float* __restrict__ ee1, const float* __restrict__ ee2,
                            const float* __restrict__ b1, const float* __restrict__ b2,
                            const float* __restrict__ xe1, const float* __restrict__ xe2,
                            unsigned short* __restrict__ wt1, unsigned short* __restrict__ wt2,
                            float* __restrict__ combo, float* __restrict__ selfv,
                            float* __restrict__ b1p, float* __restrict__ b2p,
                            float* __restrict__ e1p, float* __restrict__ e2p,
                            float* __restrict__ bnAB, float* __restrict__ bnacc) {
  int i = blockIdx.x * 256 + threadIdx.x;
  if (i < 5 * PER_L) {
    int l = i / PER_L, j = i - l * PER_L;
    if (j < 640 * 320) {                     // wt1[l][n][k] = W1[l][k][n], pad 640x320
      int n = j / 320, k = j % 320;
      float v = (n < 600 && k < 300) ? W1[(size_t)l * 180000 + k * 600 + n] : 0.f;
      wt1[l * 204800 + j] = f2bf(v); return;
    }
    j -= 640 * 320;
    if (j < 384 * 640) {                     // wt2[l][n][k] = W2[l][k][n], pad 384x640
      int n = j / 640, k = j % 640;
      float v = (n < 300 && k < 600) ? W2[(size_t)l * 180000 + k * 300 + n] : 0.f;
      wt2[l * 245760 + j] = f2bf(v); return;
    }
    j -= 384 * 640;
    if (j < 12 * 304) {                      // combos [12][304], zero-padded
      int idx = j / 304, d = j % 304;
      int a = idx / 3, b = idx % 3;
      combo[l * 3648 + j] = (d < 300)
          ? ee1[l * 1800 + a * 300 + d] + ee2[l * 900 + b * 300 + d] : 0.f;
      return;
    }
    j -= 12 * 304;
    if (j < 304) {                           // selfv [304], zero-padded
      selfv[l * 304 + j] = (j < 300)
          ? ee1[l * 1800 + 4 * 300 + j] + ee2[l * 900 + j] : 0.f;
      return;
    }
    j -= 304;
    if (j < 640) { b1p[l * 640 + j] = (j < 600) ? b1[l * 600 + j] : 0.f; return; }
    j -= 640;
    b2p[l * 384 + j] = (j < 300) ? b2[l * 300 + j] : 0.f; return;
  }
  i -= 5 * PER_L;
  if (i < 120 * 304) {                       // padded x_emb1 [120][304]
    int n = i / 304, d = i % 304;
    e1p[i] = (d < 300) ? xe1[n * 300 + d] : 0.f; return;
  }
  i -= 120 * 304;
  if (i < 3 * 304) {                         // padded x_emb2 [3][304]
    int n = i / 304, d = i % 304;
    e2p[i] = (d < 300) ? xe2[n * 300 + d] : 0.f; return;
  }
  i -= 3 * 304;
  if (i < 2 * 384) { bnAB[i] = 0.f; return; }   // bnA|bnB zero (pads stay 0 forever)
  i -= 2 * 384;
  if (i < 5 * 2 * NSLOT * 384) bnacc[i] = 0.f;  // all BN accumulators
}

// ---------------- CSR build: degree histogram
__global__ void deg_kernel(const int* __restrict__ ei, int* __restrict__ deg) {
  int e = blockIdx.x * 256 + threadIdx.x;
  if (e >= NE) return;
  atomicAdd(&deg[ei[NE + e]], 1);
}

// ---------------- exclusive scan (3 kernels)
__global__ void scan1_kernel(const int* __restrict__ deg, int* __restrict__ off,
                             int* __restrict__ bsum) {
  __shared__ int tmp[SCAN_B];
  int b = blockIdx.x, t = threadIdx.x;
  int i = b * SCAN_B + t;
  int v = (i < NN) ? deg[i] : 0;
  tmp[t] = v;
  __syncthreads();
  for (int s = 1; s < SCAN_B; s <<= 1) {
    int a = (t >= s) ? tmp[t - s] : 0;
    __syncthreads();
    tmp[t] += a;
    __syncthreads();
  }
  if (i < NN) off[i] = tmp[t] - v;           // exclusive
  if (t == SCAN_B - 1) bsum[b] = tmp[t];
}
__global__ void scan2_kernel(int* __restrict__ bsum) {
  if (threadIdx.x == 0) {
    int acc = 0;
    for (int b = 0; b < NBLK; ++b) { int v = bsum[b]; bsum[b] = acc; acc += v; }
  }
}
__global__ void scan3_kernel(const int* __restrict__ bsum, int* __restrict__ off,
                             int* __restrict__ cursor) {
  int i = blockIdx.x * SCAN_B + threadIdx.x;
  if (i >= NN) return;
  int o = off[i] + bsum[blockIdx.x];
  off[i] = o;
  cursor[i] = o;
}

// ---------------- CSR fill: list[p] = src*16 + combo_idx
__global__ void fill_kernel(const int* __restrict__ ei, const int* __restrict__ ea,
                            int* __restrict__ cursor, int* __restrict__ list) {
  int e = blockIdx.x * 256 + threadIdx.x;
  if (e >= NE) return;
  int s = ei[e], d = ei[NE + e];
  int c = ea[2 * e] * 3 + ea[2 * e + 1];
  int p = atomicAdd(&cursor[d], 1);
  list[p] = s * 16 + c;
}

// ---------------- gather, 16B-granule, 2-way edge-unrolled.
// MODE 0: source row = e1p[x0[s]] + e2p[x1[s]]       (layer 0, padded tables)
// MODE 1: source row = relu(bf16z[s]*bnA + bnB)      (layers 1..4; z stride NZ)
template <int MODE>
__global__ void gather_kernel(const unsigned short* __restrict__ zsrc,
                              const int* __restrict__ x, const float* __restrict__ e1p,
                              const float* __restrict__ e2p,
                              const float* __restrict__ bnA, const float* __restrict__ bnB,
                              const int* __restrict__ off, const int* __restrict__ deg,
                              const int* __restrict__ list,
                              const float* __restrict__ combo, const float* __restrict__ selfv,
                              const float* __restrict__ eps, int l,
                              unsigned short* __restrict__ abf) {
  int i = blockIdx.x * 256 + threadIdx.x;
  if (i >= NN * 38) return;
  int r = i / 38, qc = i % 38;
  const int cb = qc * 8;

  float4 a0, a1, b0, b1;
  if (MODE == 1) {
    a0 = *(const float4*)(bnA + cb); a1 = *(const float4*)(bnA + cb + 4);
    b0 = *(const float4*)(bnB + cb); b1 = *(const float4*)(bnB + cb + 4);
  }

  auto loadrow = [&](int s, float4& oL, float4& oH) {
    if (MODE == 0) {
      const float* p1 = e1p + (size_t)x[2 * s] * 304 + cb;
      const float* p2 = e2p + (size_t)x[2 * s + 1] * 304 + cb;
      float4 u0 = *(const float4*)p1, u1 = *(const float4*)(p1 + 4);
      float4 v0 = *(const float4*)p2, v1 = *(const float4*)(p2 + 4);
      oL.x = u0.x + v0.x; oL.y = u0.y + v0.y; oL.z = u0.z + v0.z; oL.w = u0.w + v0.w;
      oH.x = u1.x + v1.x; oH.y = u1.y + v1.y; oH.z = u1.z + v1.z; oH.w = u1.w + v1.w;
    } else {
      u16x8 zv = *reinterpret_cast<const u16x8*>(zsrc + (size_t)s * NZ + cb);
      oL.x = fmaxf(bf2f(zv[0]) * a0.x + b0.x, 0.f);
      oL.y = fmaxf(bf2f(zv[1]) * a0.y + b0.y, 0.f);
      oL.z = fmaxf(bf2f(zv[2]) * a0.z + b0.z, 0.f);
      oL.w = fmaxf(bf2f(zv[3]) * a0.w + b0.w, 0.f);
      oH.x = fmaxf(bf2f(zv[4]) * a1.x + b1.x, 0.f);
      oH.y = fmaxf(bf2f(zv[5]) * a1.y + b1.y, 0.f);
      oH.z = fmaxf(bf2f(zv[6]) * a1.z + b1.z, 0.f);
      oH.w = fmaxf(bf2f(zv[7]) * a1.w + b1.w, 0.f);
    }
  };

  float4 accL, accH;
  loadrow(r, accL, accH);
  {
    float4 s0 = *(const float4*)(selfv + cb), s1 = *(const float4*)(selfv + cb + 4);
    accL.x += s0.x; accL.y += s0.y; accL.z += s0.z; accL.w += s0.w;
    accH.x += s1.x; accH.y += s1.y; accH.z += s1.z; accH.w += s1.w;
  }

  int p0 = off[r], dn = deg[r];
  int p = 0;
  // 2-way unroll: both list entries (same cache line) + both 16B row loads
  // issued before either accumulate -> serial latency chain halves.
  for (; p + 2 <= dn; p += 2) {
    int pk0 = list[p0 + p];
    int pk1 = list[p0 + p + 1];
    int s0i = pk0 >> 4, c0i = pk0 & 15;
    int s1i = pk1 >> 4, c1i = pk1 & 15;
    float4 h0L, h0H, h1L, h1H;
    loadrow(s0i, h0L, h0H);
    loadrow(s1i, h1L, h1H);
    const float* cp0 = combo + c0i * 304 + cb;
    const float* cp1 = combo + c1i * 304 + cb;
    float4 ca0 = *(const float4*)cp0, ca1 = *(const float4*)(cp0 + 4);
    float4 cb0 = *(const float4*)cp1, cb1 = *(const float4*)(cp1 + 4);
    accL.x += h0L.x + ca0.x; accL.y += h0L.y + ca0.y;
    accL.z += h0L.z + ca0.z; accL.w += h0L.w + ca0.w;
    accH.x += h0H.x + ca1.x; accH.y += h0H.y + ca1.y;
    accH.z += h0H.z + ca1.z; accH.w += h0H.w + ca1.w;
    accL.x += h1L.x + cb0.x; accL.y += h1L.y + cb0.y;
    accL.z += h1L.z + cb0.z; accL.w += h1L.w + cb0.w;
    accH.x += h1H.x + cb1.x; accH.y += h1H.y + cb1.y;
    accH.z += h1H.z + cb1.z; accH.w += h1H.w + cb1.w;
  }
  if (p < dn) {
    int pk = list[p0 + p];
    int s = pk >> 4, c = pk & 15;
    float4 hL, hH;
    loadrow(s, hL, hH);
    const float* cp = combo + c * 304 + cb;
    float4 c0 = *(const float4*)cp, c1 = *(const float4*)(cp + 4);
    accL.x += hL.x + c0.x; accL.y += hL.y + c0.y;
    accL.z += hL.z + c0.z; accL.w += hL.w + c0.w;
    accH.x += hH.x + c1.x; accH.y += hH.y + c1.y;
    accH.z += hH.z + c1.z; accH.w += hH.w + c1.w;
  }

  float sc = 1.f + eps[l];
  u16x8 o;
  o[0] = f2bf(accL.x * sc); o[1] = f2bf(accL.y * sc);
  o[2] = f2bf(accL.z * sc); o[3] = f2bf(accL.w * sc);
  o[4] = f2bf(accH.x * sc); o[5] = f2bf(accH.y * sc);
  o[6] = f2bf(accH.z * sc); o[7] = f2bf(accH.w * sc);
  *reinterpret_cast<u16x8*>(abf + (size_t)r * 320 + cb) = o;
}

// ---------------- bf16 MFMA GEMM (r8 structure): 8 waves, BM=256 x BN=128.
// Double-buffered LDS, counted-vmcnt prefetch, XCD remap (wid%8 = strip group).
// NSTORE: only cols < NSTORE are stored / counted (pad cols are provably zero).
// STATS: per-column sum/sumsq of output (rows < NN), slot-split 32x.
template <int LDA, int LDB, int NS, int NSTORE, int NT, bool RELU, bool OBF16, bool STATS>
__global__ __launch_bounds__(512, 4) void gemm_kernel(
    const unsigned short* __restrict__ A, const unsigned short* __restrict__ B,
    const float* __restrict__ bias, void* __restrict__ C, int K,
    float* __restrict__ bnsum, float* __restrict__ bnsum2) {
  __shared__ unsigned short As[2][256 * 32];   // 2 x 16 KB
  __shared__ unsigned short Bs[2][128 * 32];   // 2 x 8 KB
  const int tid = threadIdx.x;
  const int lane = tid & 63;
  const int w = tid >> 6;            // 8 waves: wr = w>>1 (M), wc = w&1 (N)
  const int wr = w >> 1, wc = w & 1;
  const int l15 = lane & 15, l4 = lane >> 4;

  const int wid = blockIdx.x + gridDim.x * blockIdx.y;
  const int bmi = (wid & 7) + 8 * (wid / (8 * NT));
  const int ny  = (wid >> 3) % NT;
  if (bmi >= MSTRIP) return;
  const int bm = bmi * 256;
  const int bn = ny * 128;

  auto stage = [&](int buf, int kk) {
#pragma unroll
    for (int it = 0; it < 2; ++it) {
      int s = it * 512 + tid;
      int row = s >> 2, kbl = s & 3;
      int kbg = kbl ^ ((row >> 1) & 3);        // pre-swizzled global source
      ld_lds16(A + (size_t)(bm + row) * LDA + kk + kbg * 8, &As[buf][s * 8]);
    }
    {
      int s = tid;
      int row = s >> 2, kbl = s & 3;
      int kbg = kbl ^ ((row >> 1) & 3);
      ld_lds16(B + (size_t)(bn + row) * LDB + kk + kbg * 8, &Bs[buf][s * 8]);
    }
  };

  f32x4v acc[4][4] = {};
  const int nt = K / 32;

  stage(0, 0);
  for (int t = 0; t < nt; ++t) {
    const int cur = t & 1;
    if (t + 1 < nt) {
      stage(cur ^ 1, (t + 1) * 32);                     // prefetch next tile (3 loads)
      asm volatile("s_waitcnt vmcnt(3)" ::: "memory");  // my stage(t) loads landed
    } else {
      asm volatile("s_waitcnt vmcnt(0)" ::: "memory");
    }
    __builtin_amdgcn_s_barrier();                       // raw: no vmcnt(0) drain
    asm volatile("" ::: "memory");

    bf16x8 af[4], bfr[4];
#pragma unroll
    for (int mi = 0; mi < 4; ++mi) {
      int r = wr * 64 + mi * 16 + l15;
      int kb = l4 ^ ((r >> 1) & 3);            // swizzled read
      af[mi] = *reinterpret_cast<const bf16x8*>(&As[cur][(r * 4 + kb) * 8]);
    }
#pragma unroll
    for (int ni = 0; ni < 4; ++ni) {
      int r = wc * 64 + ni * 16 + l15;
      int kb = l4 ^ ((r >> 1) & 3);
      bfr[ni] = *reinterpret_cast<const bf16x8*>(&Bs[cur][(r * 4 + kb) * 8]);
    }
#pragma unroll
    for (int mi = 0; mi < 4; ++mi)
#pragma unroll
      for (int ni = 0; ni < 4; ++ni)
        acc[mi][ni] = __builtin_amdgcn_mfma_f32_16x16x32_bf16(af[mi], bfr[ni], acc[mi][ni], 0, 0, 0);

    __builtin_amdgcn_s_barrier();                       // buf free for re-stage
    asm volatile("" ::: "memory");
  }

  const int slot = wid & (NSLOT - 1);
#pragma unroll
  for (int ni = 0; ni < 4; ++ni) {
    int col = bn + wc * 64 + ni * 16 + l15;
    if (col >= NSTORE) continue;               // pad cols: provably zero, skip
    float bv = bias[col];
    float s = 0.f, s2 = 0.f;
#pragma unroll
    for (int mi = 0; mi < 4; ++mi) {
      int row0 = bm + wr * 64 + mi * 16 + (l4 << 2);
#pragma unroll
      for (int r = 0; r < 4; ++r) {
        float v = acc[mi][ni][r] + bv;
        if (RELU) v = fmaxf(v, 0.f);
        if (OBF16) ((unsigned short*)C)[(size_t)(row0 + r) * NS + col] = f2bf(v);
        else       ((float*)C)[(size_t)(row0 + r) * NS + col] = v;
        if (STATS && (row0 + r) < NN) { s += v; s2 += v * v; }
      }
    }
    if (STATS) {
      s  += __shfl_xor(s, 16);  s  += __shfl_xor(s, 32);
      s2 += __shfl_xor(s2, 16); s2 += __shfl_xor(s2, 32);
      if (l4 == 0) {
        atomicAdd(&bnsum[slot * 384 + col], s);
        atomicAdd(&bnsum2[slot * 384 + col], s2);
      }
    }
  }
}

__global__ void bnfinal_kernel(const float* __restrict__ bnsum, const float* __restrict__ bnsum2,
                               const float* __restrict__ gamma, const float* __restrict__ beta,
                               int l, float* __restrict__ Aout, float* __restrict__ Bout) {
  int c = threadIdx.x;
  if (c >= 300) return;
  float s = 0.f, s2 = 0.f;
  for (int k = 0; k < NSLOT; ++k) { s += bnsum[k * 384 + c]; s2 += bnsum2[k * 384 + c]; }
  float mean = s * (1.f / NN);
  float var = s2 * (1.f / NN) - mean * mean;
  var = fmaxf(var, 0.f);
  float inv = rsqrtf(var + 1e-5f);
  float a = gamma[l * 300 + c] * inv;
  Aout[c] = a;
  Bout[c] = beta[l * 300 + c] - mean * a;
}

// ---------------- final BN apply (layer 4, no ReLU): d_out[N][300] = bf2f(z)*A + B
__global__ void bnapply_kernel(const unsigned short* __restrict__ z, const float* __restrict__ Ain,
                               const float* __restrict__ Bin, float* __restrict__ out) {
  int i = blockIdx.x * 256 + threadIdx.x;
  if (i >= NN * 75) return;
  int r = i / 75, q = i % 75;
  ushort4 zv = ((const ushort4*)z)[(size_t)r * (NZ / 4) + q];
  float4 a = ((const float4*)Ain)[q];
  float4 b = ((const float4*)Bin)[q];
  float4 o;
  o.x = bf2f(zv.x) * a.x + b.x; o.y = bf2f(zv.y) * a.y + b.y;
  o.z = bf2f(zv.z) * a.z + b.z; o.w = bf2f(zv.w) * a.w + b.w;
  ((float4*)out)[i] = o;
}

// ---------------- workspace layout (bytes; every increment is 16B-aligned)
constexpr size_t OFF_Z    = 0;                                    // z bf16 [MP][320]
constexpr size_t OFF_AB   = OFF_Z   + (size_t)MP * NZ * 2;        // abf16 [MP][320]
constexpr size_t OFF_Z1   = OFF_AB  + (size_t)MP * 320 * 2;       // z1 bf16 [MP][608]
constexpr size_t OFF_WT1  = OFF_Z1  + (size_t)MP * N1 * 2;        // wt1 [5][640*320]
constexpr size_t OFF_WT2  = OFF_WT1 + (size_t)5 * 204800 * 2;     // wt2 [5][384*640]
constexpr size_t OFF_CMB  = OFF_WT2 + (size_t)5 * 245760 * 2;     // combo f32 [5][12][304]
constexpr size_t OFF_SLF  = OFF_CMB + 5 * 3648 * 4;               // selfv f32 [5][304]
constexpr size_t OFF_E1P  = OFF_SLF + 5 * 304 * 4;                // e1p f32 [120][304]
constexpr size_t OFF_E2P  = OFF_E1P + 120 * 304 * 4;              // e2p f32 [3][304]
constexpr size_t OFF_B1   = OFF_E2P + 3 * 304 * 4;                // b1p f32 [5][640]
constexpr size_t OFF_B2   = OFF_B1  + 5 * 640 * 4;                // b2p f32 [5][384]
constexpr size_t OFF_S1   = OFF_B2  + 5 * 384 * 4;                // bnsum  [5][32][384]
constexpr size_t OFF_S2   = OFF_S1  + (size_t)5 * NSLOT * 384 * 4;// bnsum2 (contiguous)
constexpr size_t OFF_BA   = OFF_S2  + (size_t)5 * NSLOT * 384 * 4;// bnA f32 [384]
constexpr size_t OFF_BB   = OFF_BA + 1536;                        // bnB f32 [384]
constexpr size_t OFF_DEG  = OFF_BB + 1536;              // int[NN]
constexpr size_t OFF_OFFS = OFF_DEG + 400384;           // int[NN]
constexpr size_t OFF_CUR  = OFF_OFFS + 400384;          // int[NN]
constexpr size_t OFF_BS   = OFF_CUR + 400384;           // int[NBLK]
constexpr size_t OFF_LIST = OFF_BS + 2048;              // int[NE]

extern "C" void kernel_launch(void* const* d_in, const int* in_sizes, int n_in,
                              void* d_out, int out_size, void* d_ws, size_t ws_size,
                              hipStream_t stream) {
  const int*   x     = (const int*)d_in[0];
  const int*   ei    = (const int*)d_in[1];
  const int*   ea    = (const int*)d_in[2];
  const float* xe1   = (const float*)d_in[3];
  const float* xe2   = (const float*)d_in[4];
  const float* ee1   = (const float*)d_in[5];
  const float* ee2   = (const float*)d_in[6];
  const float* W1    = (const float*)d_in[7];
  const float* b1    = (const float*)d_in[8];
  const float* W2    = (const float*)d_in[9];
  const float* b2    = (const float*)d_in[10];
  const float* eps   = (const float*)d_in[11];
  const float* gamma = (const float*)d_in[12];
  const float* beta  = (const float*)d_in[13];

  char* ws = (char*)d_ws;
  unsigned short* zf    = (unsigned short*)(ws + OFF_Z);
  unsigned short* abf   = (unsigned short*)(ws + OFF_AB);
  unsigned short* z1    = (unsigned short*)(ws + OFF_Z1);
  unsigned short* wt1   = (unsigned short*)(ws + OFF_WT1);
  unsigned short* wt2   = (unsigned short*)(ws + OFF_WT2);
  float*          combo = (float*)(ws + OFF_CMB);
  float*          selfv = (float*)(ws + OFF_SLF);
  float*          e1p   = (float*)(ws + OFF_E1P);
  float*          e2p   = (float*)(ws + OFF_E2P);
  float*          b1p   = (float*)(ws + OFF_B1);
  float*          b2p   = (float*)(ws + OFF_B2);
  float*          bns   = (float*)(ws + OFF_S1);
  float*          bns2  = (float*)(ws + OFF_S2);
  float*          bnA   = (float*)(ws + OFF_BA);
  float*          bnB   = (float*)(ws + OFF_BB);
  int*            deg   = (int*)(ws + OFF_DEG);
  int*            offs  = (int*)(ws + OFF_OFFS);
  int*            cur   = (int*)(ws + OFF_CUR);
  int*            bsum  = (int*)(ws + OFF_BS);
  int*            list  = (int*)(ws + OFF_LIST);

  const int g_g    = (NN * 38 + 255) / 256;   // gather: 16B chunks
  const int g_ew   = (NN * 75 + 255) / 256;   // bnapply: float4 chunks
  const int g_e    = (NE + 255) / 256;
  const int g_prep = (PREP_TOT + 255) / 256;
  const int GX     = 392;   // 49 groups of 8 row-strips (1 idle strip: 391)

  // one-time per launch: zero abf (cols 304..319 stay 0 across layers), deg
  hipMemsetAsync(abf, 0, (size_t)MP * 320 * 2, stream);
  hipMemsetAsync(deg, 0, NN * 4, stream);

  // all-layer prep (weights, combos, selfv, biases, padded emb tables, BN zeroing)
  prep_kernel<<<g_prep, 256, 0, stream>>>(W1, W2, ee1, ee2, b1, b2, xe1, xe2,
                                          wt1, wt2, combo, selfv, b1p, b2p,
                                          e1p, e2p, bnA, bns);

  // CSR build (graph static across layers)
  deg_kernel<<<g_e, 256, 0, stream>>>(ei, deg);
  scan1_kernel<<<NBLK, SCAN_B, 0, stream>>>(deg, offs, bsum);
  scan2_kernel<<<1, 64, 0, stream>>>(bsum);
  scan3_kernel<<<NBLK, SCAN_B, 0, stream>>>(bsum, offs, cur);
  fill_kernel<<<g_e, 256, 0, stream>>>(ei, ea, cur, list);

  for (int l = 0; l < 5; ++l) {
    float* bns_l  = bns  + (size_t)l * NSLOT * 384;
    float* bns2_l = bns2 + (size_t)l * NSLOT * 384;
    if (l == 0)
      gather_kernel<0><<<g_g, 256, 0, stream>>>(zf, x, e1p, e2p, bnA, bnB,
                                                offs, deg, list, combo + l * 3648,
                                                selfv + l * 304, eps, l, abf);
    else
      gather_kernel<1><<<g_g, 256, 0, stream>>>(zf, x, e1p, e2p, bnA, bnB,
                                                offs, deg, list, combo + l * 3648,
                                                selfv + l * 304, eps, l, abf);
    // GEMM1: [MP][320] @ wt1^T -> z1 [MP][608]
    gemm_kernel<320, 320, N1, N1, 5, true, true, false><<<dim3(GX, 5), 512, 0, stream>>>(
        abf, wt1 + (size_t)l * 204800, b1p + l * 640, (void*)z1, 320, bns_l, bns2_l);
    // GEMM2: z1 [MP][608] @ wt2^T (K=608) -> z [MP][320]
    gemm_kernel<N1, 640, NZ, NZ, 3, false, true, true><<<dim3(GX, 3), 512, 0, stream>>>(
        z1, wt2 + (size_t)l * 245760, b2p + l * 384, (void*)zf, N1, bns_l, bns2_l);
    bnfinal_kernel<<<1, 384, 0, stream>>>(bns_l, bns2_l, gamma, beta, l, bnA, bnB);
  }
  bnapply_kernel<<<g_ew, 256, 0, stream>>>(zf, bnA, bnB, (float*)d_out);
}